// Round 8
// baseline (8690.770 us; speedup 1.0000x reference)
//
#include <hip/hip_runtime.h>
#include <hip/hip_cooperative_groups.h>

namespace cg = cooperative_groups;

#define NROWS 1568      // BATCH * L = 8 * 196
#define MPAD  1600      // padded rows for 32-row GEMM tiles
#define LSEQ  196
#define EPS   1e-5f

typedef __attribute__((ext_vector_type(8))) short short8_t;   // 8 bf16
typedef __attribute__((ext_vector_type(8))) unsigned short ush8;
typedef __attribute__((ext_vector_type(4))) float f32x4;
typedef unsigned short ush;

__device__ __forceinline__ float silu_(float x) { return x / (1.f + expf(-x)); }

__device__ __forceinline__ ush bfh_(float f) {
  unsigned u = __float_as_uint(f);
  return (ush)((u + 0x7FFFu + ((u >> 16) & 1u)) >> 16);
}
__device__ __forceinline__ float bf2f_(ush h) {
  return __uint_as_float(((unsigned)h) << 16);
}

// ---------------- split fp32 -> bf16 hi/lo ----------------
__global__ __launch_bounds__(256) void wsplit_k(const float* __restrict__ src,
                                                ush* __restrict__ hi,
                                                ush* __restrict__ lo,
                                                int n8) {
  int i = blockIdx.x * 256 + threadIdx.x;
  if (i >= n8) return;
  float v[8];
  *(float4*)&v[0] = *(const float4*)(src + (size_t)i * 8);
  *(float4*)&v[4] = *(const float4*)(src + (size_t)i * 8 + 4);
  ush8 h8, l8;
#pragma unroll
  for (int j = 0; j < 8; ++j) {
    ush h = bfh_(v[j]);
    h8[j] = h;
    l8[j] = bfh_(v[j] - bf2f_(h));
  }
  *(ush8*)&hi[(size_t)i * 8] = h8;
  *(ush8*)&lo[(size_t)i * 8] = l8;
}

// ---------------- zero res + pad rows of bf16 activation buffers ----------------
__global__ __launch_bounds__(256) void zeros_k(float* __restrict__ res,
                                               ush* __restrict__ a_h, ush* __restrict__ a_l,
                                               ush* __restrict__ hn_h, ush* __restrict__ hn_l,
                                               ush* __restrict__ y_h, ush* __restrict__ y_l) {
  int i = blockIdx.x * 256 + threadIdx.x;
  ush8 z = {};
  if (i < 75264) ((float4*)res)[i] = float4{0.f, 0.f, 0.f, 0.f};
  if (i < 3072) {
    ((ush8*)(a_h + (size_t)NROWS * 768))[i] = z;
    ((ush8*)(a_l + (size_t)NROWS * 768))[i] = z;
  }
  if (i < 768) {
    ((ush8*)(hn_h + (size_t)NROWS * 192))[i] = z;
    ((ush8*)(hn_l + (size_t)NROWS * 192))[i] = z;
  }
  if (i < 1536) {
    ((ush8*)(y_h + (size_t)NROWS * 384))[i] = z;
    ((ush8*)(y_l + (size_t)NROWS * 384))[i] = z;
  }
}

// ---------------- im2col for patch embedding, bf16 hi/lo out ----------------
__global__ __launch_bounds__(256) void im2col_k(const float* __restrict__ x,
                                                ush* __restrict__ Ah,
                                                ush* __restrict__ Al) {
  int i8 = blockIdx.x * 256 + threadIdx.x;
  if (i8 >= NROWS * 768 / 8) return;
  int idx = i8 * 8;
  int m = idx / 768, r = idx - m * 768;
  int b = m / LSEQ, l = m - b * LSEQ;
  int ph = l / 14, pw = l - ph * 14;
  int c = r >> 8, rem = r & 255, ii = rem >> 4, j = rem & 15;
  const float* src = &x[((b * 3 + c) * 224 + ph * 16 + ii) * 224 + pw * 16 + j];
  float v[8];
  *(float4*)&v[0] = *(const float4*)&src[0];
  *(float4*)&v[4] = *(const float4*)&src[4];
  ush8 h8, l8;
#pragma unroll
  for (int k = 0; k < 8; ++k) {
    ush h = bfh_(v[k]);
    h8[k] = h;
    l8[k] = bfh_(v[k] - bf2f_(h));
  }
  *(ush8*)&Ah[idx] = h8;
  *(ush8*)&Al[idx] = l8;
}

// ---------------- device GEMM: tile 32 x BN, BK=32, 4 waves ----------------
template<int BN>
__device__ __forceinline__ void gemm_dev(const ush* __restrict__ Ah_g, const ush* __restrict__ Al_g,
                                         const ush* __restrict__ Wh_g, const ush* __restrict__ Wl_g,
                                         const float* __restrict__ bias,
                                         float* __restrict__ C, int N, int K,
                                         int blk, int nblocks, int tid,
                                         ush* sAh, ush* sAl, ush* sWh, ush* sWl) {
  constexpr int NJT = BN / 32;
  const int lane = tid & 63, wave = tid >> 6;
  const int wrow = wave & 1, wcol = wave >> 1;
  const int fr = lane & 15, fg = lane >> 4;
  const int ntiles = N / BN;
  const int tiles = (MPAD / 32) * ntiles;
  const int asrow = (tid & 127) >> 2, asch = tid & 3;
  const bool doA = tid < 128;
  const int wr = (BN == 64) ? (tid >> 2) : ((tid - 128) >> 2);
  const bool doW = (BN == 64) ? true : (tid >= 128);

  for (int t = blk; t < tiles; t += nblocks) {
    int row0 = (t / ntiles) * 32;
    int col0 = (t - (t / ntiles) * ntiles) * BN;
    f32x4 acc[NJT];
#pragma unroll
    for (int j = 0; j < NJT; ++j) acc[j] = f32x4{0.f, 0.f, 0.f, 0.f};

    for (int kk = 0; kk < K; kk += 32) {
      ush8 va_h, va_l, vw_h, vw_l;
      if (doA) {
        size_t ga = (size_t)(row0 + asrow) * K + kk + asch * 8;
        va_h = *(const ush8*)&Ah_g[ga];
        va_l = *(const ush8*)&Al_g[ga];
      }
      if (doW) {
        size_t gw = (size_t)(col0 + wr) * K + kk + asch * 8;
        vw_h = *(const ush8*)&Wh_g[gw];
        vw_l = *(const ush8*)&Wl_g[gw];
      }
      __syncthreads();
      if (doA) {
        int d = asrow * 32 + ((asch ^ ((asrow >> 1) & 3)) << 3);
        *(ush8*)&sAh[d] = va_h;
        *(ush8*)&sAl[d] = va_l;
      }
      if (doW) {
        int d = wr * 32 + ((asch ^ ((wr >> 1) & 3)) << 3);
        *(ush8*)&sWh[d] = vw_h;
        *(ush8*)&sWl[d] = vw_l;
      }
      __syncthreads();

      int ra = wrow * 16 + fr;
      int oa = ra * 32 + ((fg ^ ((ra >> 1) & 3)) << 3);
      short8_t ah = *(short8_t*)&sAh[oa];
      short8_t al = *(short8_t*)&sAl[oa];
#pragma unroll
      for (int jt = 0; jt < NJT; ++jt) {
        int rw = wcol * (BN / 2) + jt * 16 + fr;
        int ow = rw * 32 + ((fg ^ ((rw >> 1) & 3)) << 3);
        short8_t wh = *(short8_t*)&sWh[ow];
        short8_t wl = *(short8_t*)&sWl[ow];
        acc[jt] = __builtin_amdgcn_mfma_f32_16x16x32_bf16(ah, wh, acc[jt], 0, 0, 0);
        acc[jt] = __builtin_amdgcn_mfma_f32_16x16x32_bf16(ah, wl, acc[jt], 0, 0, 0);
        acc[jt] = __builtin_amdgcn_mfma_f32_16x16x32_bf16(al, wh, acc[jt], 0, 0, 0);
      }
    }
#pragma unroll
    for (int jt = 0; jt < NJT; ++jt)
#pragma unroll
      for (int r = 0; r < 4; ++r) {
        int m = row0 + wrow * 16 + fg * 4 + r;
        int n = col0 + wcol * (BN / 2) + jt * 16 + fr;
        float o = acc[jt][r];
        if (bias) o += bias[n];
        C[(size_t)m * N + n] = o;
      }
  }
}

// ---------------- residual-add + LayerNorm core (1 wave per row) ----------------
__device__ __forceinline__ void addln_core(float* __restrict__ res, const float* __restrict__ h,
                                           const float* __restrict__ w, const float* __restrict__ b,
                                           int n, int lane, float o[3]) {
  float v[3];
  float s = 0.f;
#pragma unroll
  for (int i = 0; i < 3; ++i) {
    int d = lane + 64 * i;
    float r = res[(size_t)n * 192 + d] + h[(size_t)n * 192 + d];
    res[(size_t)n * 192 + d] = r;
    v[i] = r;
    s += r;
  }
#pragma unroll
  for (int off = 32; off >= 1; off >>= 1) s += __shfl_xor(s, off);
  float mu = s * (1.f / 192.f);
  float q = 0.f;
#pragma unroll
  for (int i = 0; i < 3; ++i) { float dd = v[i] - mu; q += dd * dd; }
#pragma unroll
  for (int off = 32; off >= 1; off >>= 1) q += __shfl_xor(q, off);
  float inv = rsqrtf(q * (1.f / 192.f) + EPS);
#pragma unroll
  for (int i = 0; i < 3; ++i) {
    int d = lane + 64 * i;
    o[i] = (v[i] - mu) * inv * w[d] + b[d];
  }
}

// ---------------- conv4+SiLU + x_proj + dt_proj core (1 wave per row) ----------------
__device__ __forceinline__ void convdt_dev(int n, bool act, int lane,
                                           const float* __restrict__ xz,
                                           const float* __restrict__ cwL, const float* __restrict__ cbL,
                                           const float* __restrict__ xpwL,
                                           const float* __restrict__ dtwL, const float* __restrict__ dtbL,
                                           float* __restrict__ xc, float* __restrict__ dbl,
                                           float* __restrict__ dt,
                                           float* __restrict__ xclw, float* __restrict__ dbllw) {
  int b = n / LSEQ, l = n - b * LSEQ;
  if (act) {
#pragma unroll
    for (int j = 0; j < 6; ++j) {
      int d = lane + 64 * j;
      float acc = cbL[d];
      const float* cw = cwL + d * 4;
#pragma unroll
      for (int k = 0; k < 4; ++k) {
        int ll = l - 3 + k;
        if (ll >= 0) acc += xz[(size_t)(n - 3 + k) * 768 + d] * cw[k];
      }
      float xcv = silu_(acc);
      xclw[d] = xcv;
      xc[(size_t)n * 384 + d] = xcv;
    }
  }
  __syncthreads();
  if (act && lane < 44) {
    const float4* xr = (const float4*)xclw;
    const float4* wr4 = (const float4*)(xpwL + (size_t)lane * 384);
    float s2 = 0.f;
#pragma unroll
    for (int k = 0; k < 96; ++k) {
      float4 a4 = xr[k], b4 = wr4[k];
      s2 += a4.x * b4.x + a4.y * b4.y + a4.z * b4.z + a4.w * b4.w;
    }
    dbllw[lane] = s2;
    dbl[(size_t)n * 44 + lane] = s2;
  }
  __syncthreads();
  if (act) {
#pragma unroll
    for (int j = 0; j < 6; ++j) {
      int d = lane + 64 * j;
      float a = dtbL[d];
      const float* dw = dtwL + (size_t)d * 12;
#pragma unroll
      for (int r = 0; r < 12; ++r) a += dbllw[r] * dw[r];
      float sp = fmaxf(a, 0.f) + log1pf(expf(-fabsf(a)));
      dt[(size_t)n * 384 + d] = sp;
    }
  }
}

// ---------------- selective scan core (1 wave per (b,d); 4 chunks x 49) ----------------
__device__ __forceinline__ void scan_dev(int bd, int lane,
                                         const float* __restrict__ dt, const float* __restrict__ xc,
                                         const float* __restrict__ dbl, const float* __restrict__ xz,
                                         const float* __restrict__ alL, const float* __restrict__ dpL,
                                         ush* __restrict__ y_h, ush* __restrict__ y_l) {
  int b = bd / 384, d = bd - b * 384;
  int c = lane >> 4, s = lane & 15;
  float A = -expf(alL[(size_t)d * 16 + s]);
  float Dp = dpL[d];
  int n0 = b * LSEQ + c * 49;
  float h = 0.f, pr = 1.f;
  for (int i = 0; i < 49; ++i) {
    int n = n0 + i;
    float dtv = dt[(size_t)n * 384 + d];
    float xcv = xc[(size_t)n * 384 + d];
    float Bv = dbl[(size_t)n * 44 + 12 + s];
    float a = expf(dtv * A);
    h = a * h + dtv * xcv * Bv;
    pr *= a;
  }
  float h0 = 0.f;
#pragma unroll
  for (int cc = 0; cc < 3; ++cc) {
    float pc = __shfl(pr, cc * 16 + s);
    float sc = __shfl(h, cc * 16 + s);
    if (cc < c) h0 = pc * h0 + sc;
  }
  h = h0;
  for (int i = 0; i < 49; ++i) {
    int n = n0 + i;
    float dtv = dt[(size_t)n * 384 + d];
    float xcv = xc[(size_t)n * 384 + d];
    float Bv = dbl[(size_t)n * 44 + 12 + s];
    float Cv = dbl[(size_t)n * 44 + 28 + s];
    float a = expf(dtv * A);
    h = a * h + dtv * xcv * Bv;
    float ps = h * Cv;
    ps += __shfl_xor(ps, 1);
    ps += __shfl_xor(ps, 2);
    ps += __shfl_xor(ps, 4);
    ps += __shfl_xor(ps, 8);
    if (s == 0) {
      float zv = xz[(size_t)n * 768 + 384 + d];
      float o = (ps + Dp * xcv) * silu_(zv);
      ush hh = bfh_(o);
      y_h[(size_t)n * 384 + d] = hh;
      y_l[(size_t)n * 384 + d] = bfh_(o - bf2f_(hh));
    }
  }
}

// ---------------- cooperative mega kernel ----------------
struct MegaP {
  const float *norm_w, *norm_b, *conv_w, *conv_b, *x_proj_w, *dt_proj_w, *dt_proj_b;
  const float *A_log, *D_param, *normf_w, *normf_b;
  const ush *ipw_h, *ipw_l, *opw_h, *opw_l;
  float *res, *h, *xz, *xc, *dbl, *dt, *out;
  ush *hn_h, *hn_l, *y_h, *y_l;
};

__global__ __launch_bounds__(256, 2) void mega_k(MegaP p) {
  __shared__ ush sAh[1024], sAl[1024], sWh[2048], sWl[2048];
  __shared__ float xcl[4][384];
  __shared__ float dbll[4][48];
  cg::grid_group grid = cg::this_grid();
  const int tid = threadIdx.x, blk = blockIdx.x;
  const int lane = tid & 63, wave = tid >> 6;
  const int nw = gridDim.x * 4;
  const int gw = blk * 4 + wave;

  for (int L = 0; L < 24; ++L) {
    // stage 1: residual-add + LN -> hn (bf16 hi/lo)
    for (int n = gw; n < NROWS; n += nw) {
      float o[3];
      addln_core(p.res, p.h, p.norm_w + L * 192, p.norm_b + L * 192, n, lane, o);
#pragma unroll
      for (int i = 0; i < 3; ++i) {
        int d = lane + 64 * i;
        ush hh = bfh_(o[i]);
        p.hn_h[(size_t)n * 192 + d] = hh;
        p.hn_l[(size_t)n * 192 + d] = bfh_(o[i] - bf2f_(hh));
      }
    }
    grid.sync();

    // stage 2: in_proj GEMM (1600x768x192)
    gemm_dev<64>(p.hn_h, p.hn_l, p.ipw_h + (size_t)L * 147456, p.ipw_l + (size_t)L * 147456,
                 nullptr, p.xz, 768, 192, blk, gridDim.x, tid, sAh, sAl, sWh, sWl);
    grid.sync();

    // stage 3: conv+x_proj+dt (uniform trip count so __syncthreads is safe)
    {
      int iters = (NROWS + nw - 1) / nw;
      for (int it = 0; it < iters; ++it) {
        int n = gw + it * nw;
        convdt_dev(n, n < NROWS, lane, p.xz,
                   p.conv_w + (size_t)L * 1536, p.conv_b + (size_t)L * 384,
                   p.x_proj_w + (size_t)L * 16896,
                   p.dt_proj_w + (size_t)L * 4608, p.dt_proj_b + (size_t)L * 384,
                   p.xc, p.dbl, p.dt, xcl[wave], dbll[wave]);
      }
    }
    grid.sync();

    // stage 4: scan
    for (int bd = gw; bd < 3072; bd += nw)
      scan_dev(bd, lane, p.dt, p.xc, p.dbl, p.xz,
               p.A_log + (size_t)L * 6144, p.D_param + (size_t)L * 384, p.y_h, p.y_l);
    grid.sync();

    // stage 5: out_proj GEMM (1600x192x384)
    gemm_dev<32>(p.y_h, p.y_l, p.opw_h + (size_t)L * 73728, p.opw_l + (size_t)L * 73728,
                 nullptr, p.h, 192, 384, blk, gridDim.x, tid, sAh, sAl, sWh, sWl);
    grid.sync();
  }

  // final residual-add + LN -> fp32 out
  for (int n = gw; n < NROWS; n += nw) {
    float o[3];
    addln_core(p.res, p.h, p.normf_w, p.normf_b, n, lane, o);
#pragma unroll
    for (int i = 0; i < 3; ++i) p.out[(size_t)n * 192 + lane + 64 * i] = o[i];
  }
}

// ---------------- fallback per-stage kernels (same device code) ----------------
__global__ __launch_bounds__(256) void ln_k(float* res, const float* h, const float* w,
                                            const float* b, ush* oh, ush* ol) {
  int n = blockIdx.x * 4 + (threadIdx.x >> 6);
  int lane = threadIdx.x & 63;
  if (n >= NROWS) return;
  float o[3];
  addln_core(res, h, w, b, n, lane, o);
#pragma unroll
  for (int i = 0; i < 3; ++i) {
    int d = lane + 64 * i;
    ush hh = bfh_(o[i]);
    oh[(size_t)n * 192 + d] = hh;
    ol[(size_t)n * 192 + d] = bfh_(o[i] - bf2f_(hh));
  }
}

__global__ __launch_bounds__(256) void lnfin_k(float* res, const float* h, const float* w,
                                               const float* b, float* out) {
  int n = blockIdx.x * 4 + (threadIdx.x >> 6);
  int lane = threadIdx.x & 63;
  if (n >= NROWS) return;
  float o[3];
  addln_core(res, h, w, b, n, lane, o);
#pragma unroll
  for (int i = 0; i < 3; ++i) out[(size_t)n * 192 + lane + 64 * i] = o[i];
}

__global__ __launch_bounds__(256) void convdt_k(const float* xz, const float* cw, const float* cb,
                                                const float* xpw, const float* dtw, const float* dtb,
                                                float* xc, float* dbl, float* dt) {
  __shared__ float xcl[4][384];
  __shared__ float dbll[4][48];
  int wave = threadIdx.x >> 6, lane = threadIdx.x & 63;
  int n = blockIdx.x * 4 + wave;
  convdt_dev(n, n < NROWS, lane, xz, cw, cb, xpw, dtw, dtb, xc, dbl, dt, xcl[wave], dbll[wave]);
}

__global__ __launch_bounds__(256) void scanS_k(const float* dt, const float* xc, const float* dbl,
                                               const float* xz, const float* al, const float* dp,
                                               ush* y_h, ush* y_l) {
  int bd = blockIdx.x * 4 + (threadIdx.x >> 6);
  scan_dev(bd, threadIdx.x & 63, dt, xc, dbl, xz, al, dp, y_h, y_l);
}

__global__ __launch_bounds__(256) void gemm64_k(const ush* Ah, const ush* Al, const ush* Wh,
                                                const ush* Wl, const float* bias, float* C,
                                                int N, int K) {
  __shared__ ush sAh[1024], sAl[1024], sWh[2048], sWl[2048];
  gemm_dev<64>(Ah, Al, Wh, Wl, bias, C, N, K, blockIdx.x, gridDim.x, threadIdx.x,
               sAh, sAl, sWh, sWl);
}

__global__ __launch_bounds__(256) void gemm32_k(const ush* Ah, const ush* Al, const ush* Wh,
                                                const ush* Wl, const float* bias, float* C,
                                                int N, int K) {
  __shared__ ush sAh[1024], sAl[1024], sWh[2048], sWl[2048];
  gemm_dev<32>(Ah, Al, Wh, Wl, bias, C, N, K, blockIdx.x, gridDim.x, threadIdx.x,
               sAh, sAl, sWh, sWl);
}

extern "C" void kernel_launch(void* const* d_in, const int* in_sizes, int n_in,
                              void* d_out, int out_size, void* d_ws, size_t ws_size,
                              hipStream_t stream) {
  const float* x        = (const float*)d_in[0];
  const float* patch_w  = (const float*)d_in[1];
  const float* patch_b  = (const float*)d_in[2];
  const float* norm_w   = (const float*)d_in[3];
  const float* norm_b   = (const float*)d_in[4];
  const float* in_proj_w  = (const float*)d_in[5];
  const float* conv_w   = (const float*)d_in[6];
  const float* conv_b   = (const float*)d_in[7];
  const float* x_proj_w = (const float*)d_in[8];
  const float* dt_proj_w = (const float*)d_in[9];
  const float* dt_proj_b = (const float*)d_in[10];
  const float* A_log    = (const float*)d_in[11];
  const float* D_param  = (const float*)d_in[12];
  const float* out_proj_w = (const float*)d_in[13];
  const float* normf_w  = (const float*)d_in[14];
  const float* normf_b  = (const float*)d_in[15];
  float* out = (float*)d_out;
  float* ws = (float*)d_ws;

  // fp32 workspace (float offsets)
  float* res = ws;                     // 301056
  float* xz  = ws + 301056;            // 1228800
  float* xc  = ws + 1529856;           // 602112
  float* dbl = ws + 2131968;           // 68992
  float* dt  = ws + 2200960;           // 602112
  float* h   = ws + 2803072;           // 307200
  // bf16 area
  ush* ub = (ush*)(ws + 3110272);
  ush* a_h  = ub;                      // 1600*768
  ush* a_l  = ub + 1228800;
  ush* hn_h = ub + 2457600;            // 1600*192
  ush* hn_l = ub + 2764800;
  ush* y_h  = ub + 3072000;            // 1600*384
  ush* y_l  = ub + 3686400;
  ush* pw_h = ub + 4300800;            // 192*768
  ush* pw_l = ub + 4448256;
  ush* ipw_h = ub + 4595712;           // 24*768*192
  ush* ipw_l = ub + 8134656;
  ush* opw_h = ub + 11673600;          // 24*192*384
  ush* opw_l = ub + 13443072;

  zeros_k<<<294, 256, 0, stream>>>(res, a_h, a_l, hn_h, hn_l, y_h, y_l);
  wsplit_k<<<(147456 / 8 + 255) / 256, 256, 0, stream>>>(patch_w, pw_h, pw_l, 147456 / 8);
  wsplit_k<<<(3538944 / 8 + 255) / 256, 256, 0, stream>>>(in_proj_w, ipw_h, ipw_l, 3538944 / 8);
  wsplit_k<<<(1769472 / 8 + 255) / 256, 256, 0, stream>>>(out_proj_w, opw_h, opw_l, 1769472 / 8);
  im2col_k<<<(NROWS * 768 / 8 + 255) / 256, 256, 0, stream>>>(x, a_h, a_l);
  gemm64_k<<<150, 256, 0, stream>>>(a_h, a_l, pw_h, pw_l, patch_b, h, 192, 768);

  MegaP mp;
  mp.norm_w = norm_w; mp.norm_b = norm_b;
  mp.conv_w = conv_w; mp.conv_b = conv_b;
  mp.x_proj_w = x_proj_w; mp.dt_proj_w = dt_proj_w; mp.dt_proj_b = dt_proj_b;
  mp.A_log = A_log; mp.D_param = D_param;
  mp.normf_w = normf_w; mp.normf_b = normf_b;
  mp.ipw_h = ipw_h; mp.ipw_l = ipw_l; mp.opw_h = opw_h; mp.opw_l = opw_l;
  mp.res = res; mp.h = h; mp.xz = xz; mp.xc = xc; mp.dbl = dbl; mp.dt = dt;
  mp.out = out;
  mp.hn_h = hn_h; mp.hn_l = hn_l; mp.y_h = y_h; mp.y_l = y_l;

  // size cooperative grid from the runtime's own occupancy
  int occ = 0;
  hipError_t oe = hipOccupancyMaxActiveBlocksPerMultiprocessor(&occ, mega_k, 256, 0);
  int ncu = 0, dev = 0;
  hipGetDevice(&dev);
  hipDeviceGetAttribute(&ncu, hipDeviceAttributeMultiprocessorCount, dev);
  if (ncu <= 0) ncu = 256;
  int nblk = (oe == hipSuccess && occ > 0) ? occ * ncu : 256;
  if (nblk > 768) nblk = 768;
  if (nblk < 64) nblk = 64;

  void* args[] = { &mp };
  hipError_t le = hipLaunchCooperativeKernel((const void*)mega_k, dim3(nblk), dim3(256),
                                             args, 0, stream);
  if (le != hipSuccess && nblk != 256) {
    nblk = 256;
    le = hipLaunchCooperativeKernel((const void*)mega_k, dim3(nblk), dim3(256), args, 0, stream);
  }
  if (le != hipSuccess) {
    // fallback: per-stage kernels (known-good structure)
    for (int L = 0; L < 24; ++L) {
      ln_k<<<392, 256, 0, stream>>>(res, h, norm_w + L * 192, norm_b + L * 192, hn_h, hn_l);
      gemm64_k<<<600, 256, 0, stream>>>(hn_h, hn_l, ipw_h + (size_t)L * 147456,
                                        ipw_l + (size_t)L * 147456, nullptr, xz, 768, 192);
      convdt_k<<<392, 256, 0, stream>>>(xz, conv_w + (size_t)L * 1536, conv_b + (size_t)L * 384,
                                        x_proj_w + (size_t)L * 16896,
                                        dt_proj_w + (size_t)L * 4608, dt_proj_b + (size_t)L * 384,
                                        xc, dbl, dt);
      scanS_k<<<768, 256, 0, stream>>>(dt, xc, dbl, xz, A_log + (size_t)L * 6144,
                                       D_param + (size_t)L * 384, y_h, y_l);
      gemm32_k<<<300, 256, 0, stream>>>(y_h, y_l, opw_h + (size_t)L * 73728,
                                        opw_l + (size_t)L * 73728, nullptr, h, 192, 384);
    }
    lnfin_k<<<392, 256, 0, stream>>>(res, h, normf_w, normf_b, out);
  }
}

// Round 9
// 2057.672 us; speedup vs baseline: 4.2236x; 4.2236x over previous
//
#include <hip/hip_runtime.h>

#define NROWS 1568      // BATCH * L = 8 * 196
#define MPAD  1600      // padded rows for GEMM tiles
#define LSEQ  196
#define EPS   1e-5f
#define TCH   14
#define NCH   14

typedef __attribute__((ext_vector_type(8))) short short8_t;   // 8 bf16
typedef __attribute__((ext_vector_type(8))) unsigned short ush8;
typedef __attribute__((ext_vector_type(4))) float f32x4;
typedef unsigned short ush;

__device__ __forceinline__ float silu_(float x) { return x / (1.f + expf(-x)); }

__device__ __forceinline__ ush bfh_(float f) {
  unsigned u = __float_as_uint(f);
  return (ush)((u + 0x7FFFu + ((u >> 16) & 1u)) >> 16);
}
__device__ __forceinline__ float bf2f_(ush h) {
  return __uint_as_float(((unsigned)h) << 16);
}

// ---------------- merged weight split: patch_w | in_proj_w | out_proj_w ----------------
#define N8_PW  18432    // 147456/8
#define N8_IPW 442368   // 3538944/8
#define N8_OPW 221184   // 1769472/8
__global__ __launch_bounds__(256) void wsplit3_k(const float* __restrict__ pw,
                                                 const float* __restrict__ ipw,
                                                 const float* __restrict__ opw,
                                                 ush* __restrict__ pw_h, ush* __restrict__ pw_l,
                                                 ush* __restrict__ ipw_h, ush* __restrict__ ipw_l,
                                                 ush* __restrict__ opw_h, ush* __restrict__ opw_l) {
  int i = blockIdx.x * 256 + threadIdx.x;
  const float* src;
  ush *hi, *lo;
  size_t off;
  if (i < N8_PW) { src = pw; hi = pw_h; lo = pw_l; off = i; }
  else if (i < N8_PW + N8_IPW) { src = ipw; hi = ipw_h; lo = ipw_l; off = i - N8_PW; }
  else if (i < N8_PW + N8_IPW + N8_OPW) { src = opw; hi = opw_h; lo = opw_l; off = i - N8_PW - N8_IPW; }
  else return;
  float v[8];
  *(float4*)&v[0] = *(const float4*)(src + off * 8);
  *(float4*)&v[4] = *(const float4*)(src + off * 8 + 4);
  ush8 h8, l8;
#pragma unroll
  for (int j = 0; j < 8; ++j) {
    ush h = bfh_(v[j]);
    h8[j] = h;
    l8[j] = bfh_(v[j] - bf2f_(h));
  }
  *(ush8*)&hi[off * 8] = h8;
  *(ush8*)&lo[off * 8] = l8;
}

// ---------------- zero pad rows of A (im2col) and y bf16 buffers ----------------
__global__ __launch_bounds__(256) void zeros_k(ush* __restrict__ a_h, ush* __restrict__ a_l,
                                               ush* __restrict__ y_h, ush* __restrict__ y_l) {
  int i = blockIdx.x * 256 + threadIdx.x;
  ush8 z = {};
  if (i < 3072) {
    ((ush8*)(a_h + (size_t)NROWS * 768))[i] = z;
    ((ush8*)(a_l + (size_t)NROWS * 768))[i] = z;
  }
  if (i < 1536) {
    ((ush8*)(y_h + (size_t)NROWS * 384))[i] = z;
    ((ush8*)(y_l + (size_t)NROWS * 384))[i] = z;
  }
}

// ---------------- im2col for patch embedding, bf16 hi/lo out ----------------
__global__ __launch_bounds__(256) void im2col_k(const float* __restrict__ x,
                                                ush* __restrict__ Ah,
                                                ush* __restrict__ Al) {
  int i8 = blockIdx.x * 256 + threadIdx.x;
  if (i8 >= NROWS * 768 / 8) return;
  int idx = i8 * 8;
  int m = idx / 768, r = idx - m * 768;
  int b = m / LSEQ, l = m - b * LSEQ;
  int ph = l / 14, pw = l - ph * 14;
  int c = r >> 8, rem = r & 255, ii = rem >> 4, j = rem & 15;
  const float* src = &x[((b * 3 + c) * 224 + ph * 16 + ii) * 224 + pw * 16 + j];
  float v[8];
  *(float4*)&v[0] = *(const float4*)&src[0];
  *(float4*)&v[4] = *(const float4*)&src[4];
  ush8 h8, l8;
#pragma unroll
  for (int k = 0; k < 8; ++k) {
    ush h = bfh_(v[k]);
    h8[k] = h;
    l8[k] = bfh_(v[k] - bf2f_(h));
  }
  *(ush8*)&Ah[idx] = h8;
  *(ush8*)&Al[idx] = l8;
}

// ---------------- in_proj MFMA GEMM (64x64 tile, R6-verified) ----------------
__global__ __launch_bounds__(256) void gemm64_k(const ush* __restrict__ Ah_g,
                                                const ush* __restrict__ Al_g,
                                                const ush* __restrict__ Wh_g,
                                                const ush* __restrict__ Wl_g,
                                                float* __restrict__ C,
                                                int N, int K) {
  __shared__ ush Ah[2048], Al[2048], Wh[2048], Wl[2048];
  int row0 = blockIdx.x * 64, col0 = blockIdx.y * 64;
  int tid = threadIdx.x;
  int lane = tid & 63, wave = tid >> 6;
  int wm = (wave & 1) * 32, wn = (wave >> 1) * 32;
  int fr = lane & 15, fg = lane >> 4;
  int srow = tid >> 2, sch = tid & 3;
  const int sdst = srow * 32 + ((sch ^ ((srow >> 1) & 3)) << 3);

  f32x4 acc[2][2] = {};

  for (int kk = 0; kk < K; kk += 32) {
    size_t ga = (size_t)(row0 + srow) * K + kk + sch * 8;
    size_t gw = (size_t)(col0 + srow) * K + kk + sch * 8;
    ush8 vah = *(const ush8*)&Ah_g[ga];
    ush8 val = *(const ush8*)&Al_g[ga];
    ush8 vwh = *(const ush8*)&Wh_g[gw];
    ush8 vwl = *(const ush8*)&Wl_g[gw];
    __syncthreads();
    *(ush8*)&Ah[sdst] = vah;
    *(ush8*)&Al[sdst] = val;
    *(ush8*)&Wh[sdst] = vwh;
    *(ush8*)&Wl[sdst] = vwl;
    __syncthreads();

    short8_t ah[2], al[2], wh[2], wl[2];
#pragma unroll
    for (int i = 0; i < 2; ++i) {
      int ra = wm + i * 16 + fr;
      int oa = ra * 32 + ((fg ^ ((ra >> 1) & 3)) << 3);
      ah[i] = *(short8_t*)&Ah[oa];
      al[i] = *(short8_t*)&Al[oa];
      int rw = wn + i * 16 + fr;
      int ow = rw * 32 + ((fg ^ ((rw >> 1) & 3)) << 3);
      wh[i] = *(short8_t*)&Wh[ow];
      wl[i] = *(short8_t*)&Wl[ow];
    }
#pragma unroll
    for (int i = 0; i < 2; ++i)
#pragma unroll
      for (int j = 0; j < 2; ++j) {
        acc[i][j] = __builtin_amdgcn_mfma_f32_16x16x32_bf16(ah[i], wh[j], acc[i][j], 0, 0, 0);
        acc[i][j] = __builtin_amdgcn_mfma_f32_16x16x32_bf16(ah[i], wl[j], acc[i][j], 0, 0, 0);
        acc[i][j] = __builtin_amdgcn_mfma_f32_16x16x32_bf16(al[i], wh[j], acc[i][j], 0, 0, 0);
      }
  }

#pragma unroll
  for (int i = 0; i < 2; ++i)
#pragma unroll
    for (int j = 0; j < 2; ++j)
#pragma unroll
      for (int r = 0; r < 4; ++r) {
        int m = row0 + wm + i * 16 + fg * 4 + r;
        int n = col0 + wn + j * 16 + fr;
        C[(size_t)m * N + n] = acc[i][j][r];
      }
}

// ---------------- GEMM (32 rows x full 192 cols) + fused residual+LN epilogue ----------------
// FINAL=false: res_out = res_in + C; hn = split-bf16(LN(res_out))
// FINAL=true:  out_f = LN(res_in + C)  (fp32, no res write)
template<bool FINAL>
__global__ __launch_bounds__(256) void gemm_ln_k(const ush* __restrict__ Ah_g,
                                                 const ush* __restrict__ Al_g,
                                                 const ush* __restrict__ Wh_g,
                                                 const ush* __restrict__ Wl_g,
                                                 const float* __restrict__ bias,
                                                 const float* __restrict__ res_in,
                                                 float* __restrict__ res_out,
                                                 const float* __restrict__ lnw,
                                                 const float* __restrict__ lnb,
                                                 ush* __restrict__ out_h,
                                                 ush* __restrict__ out_l,
                                                 float* __restrict__ out_f,
                                                 int K) {
  __shared__ ush sAh[1024], sAl[1024];
  __shared__ ush sW[2][6144];          // [hi/lo][192*32]; reused as 32x192 fp32 tile
  int row0 = blockIdx.x * 32;
  int tid = threadIdx.x;
  int lane = tid & 63, wave = tid >> 6;
  int wr16 = (wave & 1) * 16, wc96 = (wave >> 1) * 96;
  int fr = lane & 15, fg = lane >> 4;
  int ach = tid & 3;

  f32x4 acc[6] = {};

  for (int kk = 0; kk < K; kk += 32) {
    ush8 vah, val;
    if (tid < 128) {
      int arow = tid >> 2;
      size_t ga = (size_t)(row0 + arow) * K + kk + ach * 8;
      vah = *(const ush8*)&Ah_g[ga];
      val = *(const ush8*)&Al_g[ga];
    }
    ush8 vwh[3], vwl[3];
#pragma unroll
    for (int j = 0; j < 3; ++j) {
      int wrow = (tid >> 2) + 64 * j;
      size_t gw = (size_t)wrow * K + kk + ach * 8;
      vwh[j] = *(const ush8*)&Wh_g[gw];
      vwl[j] = *(const ush8*)&Wl_g[gw];
    }
    __syncthreads();
    if (tid < 128) {
      int arow = tid >> 2;
      int d = arow * 32 + ((ach ^ ((arow >> 1) & 3)) << 3);
      *(ush8*)&sAh[d] = vah;
      *(ush8*)&sAl[d] = val;
    }
#pragma unroll
    for (int j = 0; j < 3; ++j) {
      int wrow = (tid >> 2) + 64 * j;
      int d = wrow * 32 + ((ach ^ ((wrow >> 1) & 3)) << 3);
      *(ush8*)&sW[0][d] = vwh[j];
      *(ush8*)&sW[1][d] = vwl[j];
    }
    __syncthreads();

    int ra = wr16 + fr;
    int oa = ra * 32 + ((fg ^ ((ra >> 1) & 3)) << 3);
    short8_t ah = *(short8_t*)&sAh[oa];
    short8_t al = *(short8_t*)&sAl[oa];
#pragma unroll
    for (int jt = 0; jt < 6; ++jt) {
      int rw = wc96 + jt * 16 + fr;
      int ow = rw * 32 + ((fg ^ ((rw >> 1) & 3)) << 3);
      short8_t wh = *(short8_t*)&sW[0][ow];
      short8_t wl = *(short8_t*)&sW[1][ow];
      acc[jt] = __builtin_amdgcn_mfma_f32_16x16x32_bf16(ah, wh, acc[jt], 0, 0, 0);
      acc[jt] = __builtin_amdgcn_mfma_f32_16x16x32_bf16(ah, wl, acc[jt], 0, 0, 0);
      acc[jt] = __builtin_amdgcn_mfma_f32_16x16x32_bf16(al, wh, acc[jt], 0, 0, 0);
    }
  }

  // epilogue: stage C tile (32x192 fp32) in LDS, then per-row residual+LN
  __syncthreads();                      // all MFMA LDS reads done before reuse
  float* ct = (float*)&sW[0][0];        // 24576 B
#pragma unroll
  for (int jt = 0; jt < 6; ++jt)
#pragma unroll
    for (int r = 0; r < 4; ++r) {
      int ml = wr16 + fg * 4 + r;
      int n = wc96 + jt * 16 + fr;
      float o = acc[jt][r];
      if (bias) o += bias[n];
      ct[ml * 192 + n] = o;
    }
  __syncthreads();

  for (int rr = 0; rr < 8; ++rr) {
    int ml = wave * 8 + rr;
    int m = row0 + ml;
    float v[3];
    float s = 0.f;
#pragma unroll
    for (int i = 0; i < 3; ++i) {
      int c = lane + 64 * i;
      float r = ct[ml * 192 + c];
      if (res_in) r += res_in[(size_t)m * 192 + c];
      v[i] = r;
      s += r;
    }
#pragma unroll
    for (int off = 32; off >= 1; off >>= 1) s += __shfl_xor(s, off);
    float mu = s * (1.f / 192.f);
    float q = 0.f;
#pragma unroll
    for (int i = 0; i < 3; ++i) { float dd = v[i] - mu; q += dd * dd; }
#pragma unroll
    for (int off = 32; off >= 1; off >>= 1) q += __shfl_xor(q, off);
    float inv = rsqrtf(q * (1.f / 192.f) + EPS);
    bool act = m < NROWS;
    if (!FINAL) {
#pragma unroll
      for (int i = 0; i < 3; ++i) {
        int c = lane + 64 * i;
        float o = act ? (v[i] - mu) * inv * lnw[c] + lnb[c] : 0.f;
        res_out[(size_t)m * 192 + c] = act ? v[i] : 0.f;
        ush hh = bfh_(o);
        out_h[(size_t)m * 192 + c] = hh;
        out_l[(size_t)m * 192 + c] = bfh_(o - bf2f_(hh));
      }
    } else if (act) {
#pragma unroll
      for (int i = 0; i < 3; ++i) {
        int c = lane + 64 * i;
        out_f[(size_t)m * 192 + c] = (v[i] - mu) * inv * lnw[c] + lnb[c];
      }
    }
  }
}

// ---------------- fused conv4+SiLU + x_proj + dt_proj (R5/R6-verified) ----------------
__global__ __launch_bounds__(384) void convdbldt_k(const float* __restrict__ xz,
                                                   const float* __restrict__ cw,
                                                   const float* __restrict__ cb,
                                                   const float* __restrict__ xpw,
                                                   const float* __restrict__ dtw,
                                                   const float* __restrict__ dtb,
                                                   float* __restrict__ xc,
                                                   float* __restrict__ dbl,
                                                   float* __restrict__ dt) {
  __shared__ __align__(16) float xcl[384];
  __shared__ __align__(16) float dbll[48];
  int n = blockIdx.x;
  int b = n / LSEQ, l = n - b * LSEQ;
  int t = threadIdx.x;

  float acc = cb[t];
#pragma unroll
  for (int k = 0; k < 4; ++k) {
    int ll = l - 3 + k;
    if (ll >= 0) acc += xz[(size_t)(b * LSEQ + ll) * 768 + t] * cw[t * 4 + k];
  }
  float xcv = silu_(acc);
  xcl[t] = xcv;
  xc[(size_t)n * 384 + t] = xcv;
  __syncthreads();

  if (t < 352) {
    int e = t >> 3, part = t & 7;
    const float4* w4 = (const float4*)(xpw + e * 384 + part * 48);
    const float4* x4 = (const float4*)(xcl + part * 48);
    float s2 = 0.f;
#pragma unroll
    for (int k = 0; k < 12; ++k) {
      float4 a4 = x4[k], b4 = w4[k];
      s2 += a4.x * b4.x + a4.y * b4.y + a4.z * b4.z + a4.w * b4.w;
    }
    s2 += __shfl_xor(s2, 1);
    s2 += __shfl_xor(s2, 2);
    s2 += __shfl_xor(s2, 4);
    if (part == 0) {
      dbll[e] = s2;
      dbl[(size_t)n * 44 + e] = s2;
    }
  }
  __syncthreads();

  float a = dtb[t];
  {
    const float4* dw4 = (const float4*)(dtw + t * 12);
    const float4* bb4 = (const float4*)(&dbll[0]);
#pragma unroll
    for (int k = 0; k < 3; ++k) {
      float4 wv = dw4[k], bv = bb4[k];
      a += wv.x * bv.x + wv.y * bv.y + wv.z * bv.z + wv.w * bv.w;
    }
  }
  float sp = fmaxf(a, 0.f) + log1pf(expf(-fabsf(a)));
  dt[(size_t)n * 384 + t] = sp;
}

// ---------------- fused single-kernel chunked scan (R6-verified), split-bf16 y ----------------
__global__ __launch_bounds__(448) void scanF_k(const float* __restrict__ dt,
                                               const float* __restrict__ xc,
                                               const float* __restrict__ dbl,
                                               const float* __restrict__ xz,
                                               const float* __restrict__ a_log,
                                               const float* __restrict__ dpar,
                                               ush* __restrict__ y_h,
                                               ush* __restrict__ y_l) {
  __shared__ float Pl[2][NCH][17];
  __shared__ float Sl[2][NCH][17];
  int t = threadIdx.x;
  int p = t / 224;
  int r = t - p * 224;
  int c = r >> 4, s = r & 15;
  int bd = blockIdx.x * 2 + p;
  int b = bd / 384, d = bd - b * 384;
  float A = -expf(a_log[d * 16 + s]);
  float Dp = dpar[d];

  float a_c[TCH], u_c[TCH], C_c[TCH], dx_c[TCH], gz_c[TCH];
  float h = 0.f, pr = 1.f;
  int base = b * LSEQ + c * TCH;
#pragma unroll
  for (int i = 0; i < TCH; ++i) {
    int n = base + i;
    float dtv = dt[(size_t)n * 384 + d];
    float xcv = xc[(size_t)n * 384 + d];
    float Bv  = dbl[(size_t)n * 44 + 12 + s];
    float Cv  = dbl[(size_t)n * 44 + 28 + s];
    float zv  = xz[(size_t)n * 768 + 384 + d];
    float a = expf(dtv * A);
    float u = dtv * xcv * Bv;
    h = a * h + u;
    pr *= a;
    a_c[i] = a; u_c[i] = u; C_c[i] = Cv;
    dx_c[i] = Dp * xcv; gz_c[i] = silu_(zv);
  }
  Pl[p][c][s] = pr;
  Sl[p][c][s] = h;
  __syncthreads();

#pragma unroll
  for (int off = 1; off < NCH; off <<= 1) {
    float Pp = 1.f, Sp = 0.f;
    if (c >= off) { Pp = Pl[p][c - off][s]; Sp = Sl[p][c - off][s]; }
    __syncthreads();
    if (c >= off) {
      float Pc = Pl[p][c][s], Sc = Sl[p][c][s];
      Pl[p][c][s] = Pc * Pp;
      Sl[p][c][s] = Pc * Sp + Sc;
    }
    __syncthreads();
  }

  h = (c > 0) ? Sl[p][c - 1][s] : 0.f;
#pragma unroll
  for (int i = 0; i < TCH; ++i) {
    h = a_c[i] * h + u_c[i];
    float ps = h * C_c[i];
    ps += __shfl_xor(ps, 1);
    ps += __shfl_xor(ps, 2);
    ps += __shfl_xor(ps, 4);
    ps += __shfl_xor(ps, 8);
    if (s == 0) {
      int n = base + i;
      float o = (ps + dx_c[i]) * gz_c[i];
      ush hh = bfh_(o);
      y_h[(size_t)n * 384 + d] = hh;
      y_l[(size_t)n * 384 + d] = bfh_(o - bf2f_(hh));
    }
  }
}

extern "C" void kernel_launch(void* const* d_in, const int* in_sizes, int n_in,
                              void* d_out, int out_size, void* d_ws, size_t ws_size,
                              hipStream_t stream) {
  const float* x        = (const float*)d_in[0];
  const float* patch_w  = (const float*)d_in[1];
  const float* patch_b  = (const float*)d_in[2];
  const float* norm_w   = (const float*)d_in[3];
  const float* norm_b   = (const float*)d_in[4];
  const float* in_proj_w  = (const float*)d_in[5];
  const float* conv_w   = (const float*)d_in[6];
  const float* conv_b   = (const float*)d_in[7];
  const float* x_proj_w = (const float*)d_in[8];
  const float* dt_proj_w = (const float*)d_in[9];
  const float* dt_proj_b = (const float*)d_in[10];
  const float* A_log    = (const float*)d_in[11];
  const float* D_param  = (const float*)d_in[12];
  const float* out_proj_w = (const float*)d_in[13];
  const float* normf_w  = (const float*)d_in[14];
  const float* normf_b  = (const float*)d_in[15];
  float* out = (float*)d_out;
  float* ws = (float*)d_ws;

  // fp32 workspace (float offsets)
  float* xz   = ws;                    // 1600*768 = 1228800
  float* xc   = ws + 1228800;          // 1568*384 = 602112
  float* dbl  = ws + 1830912;          // 1568*44  = 68992
  float* dt   = ws + 1899904;          // 1568*384 = 602112
  float* resA = ws + 2502016;          // 1600*192 = 307200
  float* resB = ws + 2809216;          // 1600*192 = 307200
  // bf16 area
  ush* ub = (ush*)(ws + 3116416);
  ush* a_h  = ub;                      // 1600*768
  ush* a_l  = ub + 1228800;
  ush* hn_h = ub + 2457600;            // 1600*192
  ush* hn_l = ub + 2764800;
  ush* y_h  = ub + 3072000;            // 1600*384
  ush* y_l  = ub + 3686400;
  ush* pw_h = ub + 4300800;            // 192*768
  ush* pw_l = ub + 4448256;
  ush* ipw_h = ub + 4595712;           // 24*768*192
  ush* ipw_l = ub + 8134656;
  ush* opw_h = ub + 11673600;          // 24*192*384
  ush* opw_l = ub + 13443072;          // end 15212544 ush

  zeros_k<<<12, 256, 0, stream>>>(a_h, a_l, y_h, y_l);
  wsplit3_k<<<(N8_PW + N8_IPW + N8_OPW + 255) / 256, 256, 0, stream>>>(
      patch_w, in_proj_w, out_proj_w, pw_h, pw_l, ipw_h, ipw_l, opw_h, opw_l);
  im2col_k<<<(NROWS * 768 / 8 + 255) / 256, 256, 0, stream>>>(x, a_h, a_l);

  // patch embedding GEMM + bias + LN(layer0) epilogue: res_in=0 -> resA, hn
  gemm_ln_k<false><<<MPAD / 32, 256, 0, stream>>>(
      a_h, a_l, pw_h, pw_l, patch_b, nullptr, resA,
      norm_w, norm_b, hn_h, hn_l, nullptr, 768);

  for (int L = 0; L < 24; ++L) {
    gemm64_k<<<dim3(MPAD / 64, 768 / 64), 256, 0, stream>>>(
        hn_h, hn_l, ipw_h + (size_t)L * 147456, ipw_l + (size_t)L * 147456, xz, 768, 192);
    convdbldt_k<<<NROWS, 384, 0, stream>>>(xz,
        conv_w + (size_t)L * 1536, conv_b + (size_t)L * 384,
        x_proj_w + (size_t)L * 16896,
        dt_proj_w + (size_t)L * 4608, dt_proj_b + (size_t)L * 384,
        xc, dbl, dt);
    scanF_k<<<dim3(8 * 384 / 2), 448, 0, stream>>>(dt, xc, dbl, xz,
        A_log + (size_t)L * 6144, D_param + (size_t)L * 384, y_h, y_l);
    const float* rin = (L & 1) ? resB : resA;
    float* rout = (L & 1) ? resA : resB;
    if (L < 23) {
      gemm_ln_k<false><<<MPAD / 32, 256, 0, stream>>>(
          y_h, y_l, opw_h + (size_t)L * 73728, opw_l + (size_t)L * 73728, nullptr,
          rin, rout, norm_w + (L + 1) * 192, norm_b + (L + 1) * 192,
          hn_h, hn_l, nullptr, 384);
    } else {
      gemm_ln_k<true><<<MPAD / 32, 256, 0, stream>>>(
          y_h, y_l, opw_h + (size_t)L * 73728, opw_l + (size_t)L * 73728, nullptr,
          rin, nullptr, normf_w, normf_b, nullptr, nullptr, out, 384);
    }
  }
}

// Round 10
// 1708.933 us; speedup vs baseline: 5.0855x; 1.2041x over previous
//
#include <hip/hip_runtime.h>

#define NROWS 1568      // BATCH * L = 8 * 196
#define MPAD  1600      // padded rows for GEMM tiles
#define LSEQ  196
#define EPS   1e-5f
#define TCH   14
#define NCH   14

typedef __attribute__((ext_vector_type(8))) short short8_t;   // 8 bf16
typedef __attribute__((ext_vector_type(8))) unsigned short ush8;
typedef __attribute__((ext_vector_type(4))) float f32x4;
typedef unsigned short ush;

__device__ __forceinline__ float silu_(float x) { return x / (1.f + expf(-x)); }

__device__ __forceinline__ ush bfh_(float f) {
  unsigned u = __float_as_uint(f);
  return (ush)((u + 0x7FFFu + ((u >> 16) & 1u)) >> 16);
}
__device__ __forceinline__ float bf2f_(ush h) {
  return __uint_as_float(((unsigned)h) << 16);
}

// ---------------- merged weight split: patch_w | in_proj_w | out_proj_w ----------------
#define N8_PW  18432
#define N8_IPW 442368
#define N8_OPW 221184
__global__ __launch_bounds__(256) void wsplit3_k(const float* __restrict__ pw,
                                                 const float* __restrict__ ipw,
                                                 const float* __restrict__ opw,
                                                 ush* __restrict__ pw_h, ush* __restrict__ pw_l,
                                                 ush* __restrict__ ipw_h, ush* __restrict__ ipw_l,
                                                 ush* __restrict__ opw_h, ush* __restrict__ opw_l) {
  int i = blockIdx.x * 256 + threadIdx.x;
  const float* src;
  ush *hi, *lo;
  size_t off;
  if (i < N8_PW) { src = pw; hi = pw_h; lo = pw_l; off = i; }
  else if (i < N8_PW + N8_IPW) { src = ipw; hi = ipw_h; lo = ipw_l; off = i - N8_PW; }
  else if (i < N8_PW + N8_IPW + N8_OPW) { src = opw; hi = opw_h; lo = opw_l; off = i - N8_PW - N8_IPW; }
  else return;
  float v[8];
  *(float4*)&v[0] = *(const float4*)(src + off * 8);
  *(float4*)&v[4] = *(const float4*)(src + off * 8 + 4);
  ush8 h8, l8;
#pragma unroll
  for (int j = 0; j < 8; ++j) {
    ush h = bfh_(v[j]);
    h8[j] = h;
    l8[j] = bfh_(v[j] - bf2f_(h));
  }
  *(ush8*)&hi[off * 8] = h8;
  *(ush8*)&lo[off * 8] = l8;
}

// ---------------- zero resA + pad rows of A / y bf16 buffers ----------------
__global__ __launch_bounds__(256) void zeros_k(float* __restrict__ res,
                                               ush* __restrict__ a_h, ush* __restrict__ a_l,
                                               ush* __restrict__ y_h, ush* __restrict__ y_l) {
  int i = blockIdx.x * 256 + threadIdx.x;
  ush8 z = {};
  if (i < 75264) ((float4*)res)[i] = float4{0.f, 0.f, 0.f, 0.f};
  if (i < 3072) {
    ((ush8*)(a_h + (size_t)NROWS * 768))[i] = z;
    ((ush8*)(a_l + (size_t)NROWS * 768))[i] = z;
  }
  if (i < 1536) {
    ((ush8*)(y_h + (size_t)NROWS * 384))[i] = z;
    ((ush8*)(y_l + (size_t)NROWS * 384))[i] = z;
  }
}

// ---------------- im2col for patch embedding, bf16 hi/lo out ----------------
__global__ __launch_bounds__(256) void im2col_k(const float* __restrict__ x,
                                                ush* __restrict__ Ah,
                                                ush* __restrict__ Al) {
  int i8 = blockIdx.x * 256 + threadIdx.x;
  if (i8 >= NROWS * 768 / 8) return;
  int idx = i8 * 8;
  int m = idx / 768, r = idx - m * 768;
  int b = m / LSEQ, l = m - b * LSEQ;
  int ph = l / 14, pw = l - ph * 14;
  int c = r >> 8, rem = r & 255, ii = rem >> 4, j = rem & 15;
  const float* src = &x[((b * 3 + c) * 224 + ph * 16 + ii) * 224 + pw * 16 + j];
  float v[8];
  *(float4*)&v[0] = *(const float4*)&src[0];
  *(float4*)&v[4] = *(const float4*)&src[4];
  ush8 h8, l8;
#pragma unroll
  for (int k = 0; k < 8; ++k) {
    ush h = bfh_(v[k]);
    h8[k] = h;
    l8[k] = bfh_(v[k] - bf2f_(h));
  }
  *(ush8*)&Ah[idx] = h8;
  *(ush8*)&Al[idx] = l8;
}

// ---------------- device GEMM: tile 32 x BN, BK=32, 4 waves (R8-mega-verified) ----------------
template<int BN>
__device__ __forceinline__ void gemm_dev(const ush* __restrict__ Ah_g, const ush* __restrict__ Al_g,
                                         const ush* __restrict__ Wh_g, const ush* __restrict__ Wl_g,
                                         const float* __restrict__ bias,
                                         float* __restrict__ C, int N, int K,
                                         int blk, int nblocks, int tid,
                                         ush* sAh, ush* sAl, ush* sWh, ush* sWl) {
  constexpr int NJT = BN / 32;
  const int lane = tid & 63, wave = tid >> 6;
  const int wrow = wave & 1, wcol = wave >> 1;
  const int fr = lane & 15, fg = lane >> 4;
  const int ntiles = N / BN;
  const int tiles = (MPAD / 32) * ntiles;
  const int asrow = (tid & 127) >> 2, asch = tid & 3;
  const bool doA = tid < 128;
  const int wr = (BN == 64) ? (tid >> 2) : ((tid - 128) >> 2);
  const bool doW = (BN == 64) ? true : (tid >= 128);

  for (int t = blk; t < tiles; t += nblocks) {
    int row0 = (t / ntiles) * 32;
    int col0 = (t - (t / ntiles) * ntiles) * BN;
    f32x4 acc[NJT];
#pragma unroll
    for (int j = 0; j < NJT; ++j) acc[j] = f32x4{0.f, 0.f, 0.f, 0.f};

    for (int kk = 0; kk < K; kk += 32) {
      ush8 va_h, va_l, vw_h, vw_l;
      if (doA) {
        size_t ga = (size_t)(row0 + asrow) * K + kk + asch * 8;
        va_h = *(const ush8*)&Ah_g[ga];
        va_l = *(const ush8*)&Al_g[ga];
      }
      if (doW) {
        size_t gw = (size_t)(col0 + wr) * K + kk + asch * 8;
        vw_h = *(const ush8*)&Wh_g[gw];
        vw_l = *(const ush8*)&Wl_g[gw];
      }
      __syncthreads();
      if (doA) {
        int d = asrow * 32 + ((asch ^ ((asrow >> 1) & 3)) << 3);
        *(ush8*)&sAh[d] = va_h;
        *(ush8*)&sAl[d] = va_l;
      }
      if (doW) {
        int d = wr * 32 + ((asch ^ ((wr >> 1) & 3)) << 3);
        *(ush8*)&sWh[d] = vw_h;
        *(ush8*)&sWl[d] = vw_l;
      }
      __syncthreads();

      int ra = wrow * 16 + fr;
      int oa = ra * 32 + ((fg ^ ((ra >> 1) & 3)) << 3);
      short8_t ah = *(short8_t*)&sAh[oa];
      short8_t al = *(short8_t*)&sAl[oa];
#pragma unroll
      for (int jt = 0; jt < NJT; ++jt) {
        int rw = wcol * (BN / 2) + jt * 16 + fr;
        int ow = rw * 32 + ((fg ^ ((rw >> 1) & 3)) << 3);
        short8_t wh = *(short8_t*)&sWh[ow];
        short8_t wl = *(short8_t*)&sWl[ow];
        acc[jt] = __builtin_amdgcn_mfma_f32_16x16x32_bf16(ah, wh, acc[jt], 0, 0, 0);
        acc[jt] = __builtin_amdgcn_mfma_f32_16x16x32_bf16(ah, wl, acc[jt], 0, 0, 0);
        acc[jt] = __builtin_amdgcn_mfma_f32_16x16x32_bf16(al, wh, acc[jt], 0, 0, 0);
      }
    }
#pragma unroll
    for (int jt = 0; jt < NJT; ++jt)
#pragma unroll
      for (int r = 0; r < 4; ++r) {
        int m = row0 + wrow * 16 + fg * 4 + r;
        int n = col0 + wcol * (BN / 2) + jt * 16 + fr;
        float o = acc[jt][r];
        if (bias) o += bias[n];
        C[(size_t)m * N + n] = o;
      }
  }
}

__global__ __launch_bounds__(256) void gemm64_k(const ush* Ah, const ush* Al, const ush* Wh,
                                                const ush* Wl, const float* bias, float* C,
                                                int N, int K) {
  __shared__ ush sAh[1024], sAl[1024], sWh[2048], sWl[2048];
  gemm_dev<64>(Ah, Al, Wh, Wl, bias, C, N, K, blockIdx.x, gridDim.x, threadIdx.x,
               sAh, sAl, sWh, sWl);
}

__global__ __launch_bounds__(256) void gemm32_k(const ush* Ah, const ush* Al, const ush* Wh,
                                                const ush* Wl, const float* bias, float* C,
                                                int N, int K) {
  __shared__ ush sAh[1024], sAl[1024], sWh[2048], sWl[2048];
  gemm_dev<32>(Ah, Al, Wh, Wl, bias, C, N, K, blockIdx.x, gridDim.x, threadIdx.x,
               sAh, sAl, sWh, sWl);
}

// ---------------- fused (residual+LN prologue) + in_proj GEMM ----------------
// grid = 600 blocks: tile 32 rows x 64 cols, K=192 (full K A-panel LDS-resident).
// r = res_in + hprev (col-block 0 writes res_out); A = split-bf16(LN(r)).
__global__ __launch_bounds__(256) void gemm_inln_k(const float* __restrict__ res_in,
                                                   float* __restrict__ res_out,
                                                   const float* __restrict__ hprev,
                                                   const float* __restrict__ lnw,
                                                   const float* __restrict__ lnb,
                                                   const ush* __restrict__ Wh_g,
                                                   const ush* __restrict__ Wl_g,
                                                   float* __restrict__ C) {
  __shared__ float sA[6400];            // fp32 r (32x192) then split-bf16 A (stride 200 ush)
  __shared__ ush sWh[2048], sWl[2048];
  ush* sAh = (ush*)sA;                  // [0, 6400) ush
  ush* sAl = sAh + 6400;                // [6400, 12800) ush
  const int tid = threadIdx.x;
  const int lane = tid & 63, wave = tid >> 6;
  const int t = blockIdx.x;
  const int rt = t / 12, ct = t - rt * 12;
  const int row0 = rt * 32, col0 = ct * 64;

  // phase A: r = res_in + hprev -> sA (fp32, stride 192); ct==0 writes res_out
#pragma unroll
  for (int i = 0; i < 6; ++i) {
    int idx = tid + i * 256;
    int row = idx / 48, c4 = idx - row * 48;
    size_t g = (size_t)(row0 + row) * 192 + c4 * 4;
    float4 a = *(const float4*)&res_in[g];
    float4 b = *(const float4*)&hprev[g];
    float4 r{a.x + b.x, a.y + b.y, a.z + b.z, a.w + b.w};
    *(float4*)&sA[row * 192 + c4 * 4] = r;
    if (ct == 0) *(float4*)&res_out[g] = r;
  }
  __syncthreads();

  // phase B: per-row LN (wave owns 8 rows), results in regs
  float o[8][3];
#pragma unroll
  for (int rr = 0; rr < 8; ++rr) {
    int row = wave * 8 + rr;
    float v0 = sA[row * 192 + lane];
    float v1 = sA[row * 192 + lane + 64];
    float v2 = sA[row * 192 + lane + 128];
    float s = v0 + v1 + v2;
#pragma unroll
    for (int off = 32; off >= 1; off >>= 1) s += __shfl_xor(s, off);
    float mu = s * (1.f / 192.f);
    float d0 = v0 - mu, d1 = v1 - mu, d2 = v2 - mu;
    float q = d0 * d0 + d1 * d1 + d2 * d2;
#pragma unroll
    for (int off = 32; off >= 1; off >>= 1) q += __shfl_xor(q, off);
    float inv = rsqrtf(q * (1.f / 192.f) + EPS);
    o[rr][0] = d0 * inv * lnw[lane] + lnb[lane];
    o[rr][1] = d1 * inv * lnw[lane + 64] + lnb[lane + 64];
    o[rr][2] = d2 * inv * lnw[lane + 128] + lnb[lane + 128];
  }
  __syncthreads();      // all fp32 reads done before bf16 overwrite

  // phase C: split-bf16 into swizzled A panel (stride 200 ush)
#pragma unroll
  for (int rr = 0; rr < 8; ++rr) {
    int row = wave * 8 + rr;
    int swr = (row >> 1) & 3;
#pragma unroll
    for (int i = 0; i < 3; ++i) {
      int c = lane + 64 * i;
      int sc = (c & ~31) | ((((c >> 3) & 3) ^ swr) << 3) | (c & 7);
      float x = o[rr][i];
      ush hh = bfh_(x);
      sAh[row * 200 + sc] = hh;
      sAl[row * 200 + sc] = bfh_(x - bf2f_(hh));
    }
  }

  // K-loop: K=192, A LDS-resident
  const int fr = lane & 15, fg = lane >> 4;
  const int wrow = wave & 1, wcol = wave >> 1;
  const int wr = tid >> 2, wch = tid & 3;
  f32x4 acc[2] = {};
  for (int kk = 0; kk < 192; kk += 32) {
    size_t gw = (size_t)(col0 + wr) * 192 + kk + wch * 8;
    ush8 vwh = *(const ush8*)&Wh_g[gw];
    ush8 vwl = *(const ush8*)&Wl_g[gw];
    __syncthreads();
    int d = wr * 32 + ((wch ^ ((wr >> 1) & 3)) << 3);
    *(ush8*)&sWh[d] = vwh;
    *(ush8*)&sWl[d] = vwl;
    __syncthreads();
    int ra = wrow * 16 + fr;
    int oa = ra * 200 + kk + ((fg ^ ((ra >> 1) & 3)) << 3);
    short8_t ah = *(short8_t*)&sAh[oa];
    short8_t al = *(short8_t*)&sAl[oa];
#pragma unroll
    for (int jt = 0; jt < 2; ++jt) {
      int rw = wcol * 32 + jt * 16 + fr;
      int ow = rw * 32 + ((fg ^ ((rw >> 1) & 3)) << 3);
      short8_t wh = *(short8_t*)&sWh[ow];
      short8_t wl = *(short8_t*)&sWl[ow];
      acc[jt] = __builtin_amdgcn_mfma_f32_16x16x32_bf16(ah, wh, acc[jt], 0, 0, 0);
      acc[jt] = __builtin_amdgcn_mfma_f32_16x16x32_bf16(ah, wl, acc[jt], 0, 0, 0);
      acc[jt] = __builtin_amdgcn_mfma_f32_16x16x32_bf16(al, wh, acc[jt], 0, 0, 0);
    }
  }
#pragma unroll
  for (int jt = 0; jt < 2; ++jt)
#pragma unroll
    for (int r = 0; r < 4; ++r) {
      int m = row0 + wrow * 16 + fg * 4 + r;
      int n = col0 + wcol * 32 + jt * 16 + fr;
      C[(size_t)m * 768 + n] = acc[jt][r];
    }
}

// ---------------- final residual-add + LayerNorm ----------------
__global__ __launch_bounds__(256) void lnfin_k(const float* __restrict__ res,
                                               const float* __restrict__ h,
                                               const float* __restrict__ w,
                                               const float* __restrict__ b,
                                               float* __restrict__ out) {
  int n = blockIdx.x * 4 + (threadIdx.x >> 6);
  int lane = threadIdx.x & 63;
  if (n >= NROWS) return;
  float v[3];
  float s = 0.f;
#pragma unroll
  for (int i = 0; i < 3; ++i) {
    int d = lane + 64 * i;
    float r = res[(size_t)n * 192 + d] + h[(size_t)n * 192 + d];
    v[i] = r;
    s += r;
  }
#pragma unroll
  for (int off = 32; off >= 1; off >>= 1) s += __shfl_xor(s, off);
  float mu = s * (1.f / 192.f);
  float q = 0.f;
#pragma unroll
  for (int i = 0; i < 3; ++i) { float dd = v[i] - mu; q += dd * dd; }
#pragma unroll
  for (int off = 32; off >= 1; off >>= 1) q += __shfl_xor(q, off);
  float inv = rsqrtf(q * (1.f / 192.f) + EPS);
#pragma unroll
  for (int i = 0; i < 3; ++i) {
    int d = lane + 64 * i;
    out[(size_t)n * 192 + d] = (v[i] - mu) * inv * w[d] + b[d];
  }
}

// ---------------- fused conv4+SiLU + x_proj + dt_proj (R9-verified) ----------------
__global__ __launch_bounds__(384) void convdbldt_k(const float* __restrict__ xz,
                                                   const float* __restrict__ cw,
                                                   const float* __restrict__ cb,
                                                   const float* __restrict__ xpw,
                                                   const float* __restrict__ dtw,
                                                   const float* __restrict__ dtb,
                                                   float* __restrict__ xc,
                                                   float* __restrict__ dbl,
                                                   float* __restrict__ dt) {
  __shared__ __align__(16) float xcl[384];
  __shared__ __align__(16) float dbll[48];
  int n = blockIdx.x;
  int b = n / LSEQ, l = n - b * LSEQ;
  int t = threadIdx.x;

  float acc = cb[t];
#pragma unroll
  for (int k = 0; k < 4; ++k) {
    int ll = l - 3 + k;
    if (ll >= 0) acc += xz[(size_t)(b * LSEQ + ll) * 768 + t] * cw[t * 4 + k];
  }
  float xcv = silu_(acc);
  xcl[t] = xcv;
  xc[(size_t)n * 384 + t] = xcv;
  __syncthreads();

  if (t < 352) {
    int e = t >> 3, part = t & 7;
    const float4* w4 = (const float4*)(xpw + e * 384 + part * 48);
    const float4* x4 = (const float4*)(xcl + part * 48);
    float s2 = 0.f;
#pragma unroll
    for (int k = 0; k < 12; ++k) {
      float4 a4 = x4[k], b4 = w4[k];
      s2 += a4.x * b4.x + a4.y * b4.y + a4.z * b4.z + a4.w * b4.w;
    }
    s2 += __shfl_xor(s2, 1);
    s2 += __shfl_xor(s2, 2);
    s2 += __shfl_xor(s2, 4);
    if (part == 0) {
      dbll[e] = s2;
      dbl[(size_t)n * 44 + e] = s2;
    }
  }
  __syncthreads();

  float a = dtb[t];
  {
    const float4* dw4 = (const float4*)(dtw + t * 12);
    const float4* bb4 = (const float4*)(&dbll[0]);
#pragma unroll
    for (int k = 0; k < 3; ++k) {
      float4 wv = dw4[k], bv = bb4[k];
      a += wv.x * bv.x + wv.y * bv.y + wv.z * bv.z + wv.w * bv.w;
    }
  }
  float sp = fmaxf(a, 0.f) + log1pf(expf(-fabsf(a)));
  dt[(size_t)n * 384 + t] = sp;
}

// ---------------- fused single-kernel chunked scan (R9-verified) ----------------
__global__ __launch_bounds__(448) void scanF_k(const float* __restrict__ dt,
                                               const float* __restrict__ xc,
                                               const float* __restrict__ dbl,
                                               const float* __restrict__ xz,
                                               const float* __restrict__ a_log,
                                               const float* __restrict__ dpar,
                                               ush* __restrict__ y_h,
                                               ush* __restrict__ y_l) {
  __shared__ float Pl[2][NCH][17];
  __shared__ float Sl[2][NCH][17];
  int t = threadIdx.x;
  int p = t / 224;
  int r = t - p * 224;
  int c = r >> 4, s = r & 15;
  int bd = blockIdx.x * 2 + p;
  int b = bd / 384, d = bd - b * 384;
  float A = -expf(a_log[d * 16 + s]);
  float Dp = dpar[d];

  float a_c[TCH], u_c[TCH], C_c[TCH], dx_c[TCH], gz_c[TCH];
  float h = 0.f, pr = 1.f;
  int base = b * LSEQ + c * TCH;
#pragma unroll
  for (int i = 0; i < TCH; ++i) {
    int n = base + i;
    float dtv = dt[(size_t)n * 384 + d];
    float xcv = xc[(size_t)n * 384 + d];
    float Bv  = dbl[(size_t)n * 44 + 12 + s];
    float Cv  = dbl[(size_t)n * 44 + 28 + s];
    float zv  = xz[(size_t)n * 768 + 384 + d];
    float a = expf(dtv * A);
    float u = dtv * xcv * Bv;
    h = a * h + u;
    pr *= a;
    a_c[i] = a; u_c[i] = u; C_c[i] = Cv;
    dx_c[i] = Dp * xcv; gz_c[i] = silu_(zv);
  }
  Pl[p][c][s] = pr;
  Sl[p][c][s] = h;
  __syncthreads();

#pragma unroll
  for (int off = 1; off < NCH; off <<= 1) {
    float Pp = 1.f, Sp = 0.f;
    if (c >= off) { Pp = Pl[p][c - off][s]; Sp = Sl[p][c - off][s]; }
    __syncthreads();
    if (c >= off) {
      float Pc = Pl[p][c][s], Sc = Sl[p][c][s];
      Pl[p][c][s] = Pc * Pp;
      Sl[p][c][s] = Pc * Sp + Sc;
    }
    __syncthreads();
  }

  h = (c > 0) ? Sl[p][c - 1][s] : 0.f;
#pragma unroll
  for (int i = 0; i < TCH; ++i) {
    h = a_c[i] * h + u_c[i];
    float ps = h * C_c[i];
    ps += __shfl_xor(ps, 1);
    ps += __shfl_xor(ps, 2);
    ps += __shfl_xor(ps, 4);
    ps += __shfl_xor(ps, 8);
    if (s == 0) {
      int n = base + i;
      float o = (ps + dx_c[i]) * gz_c[i];
      ush hh = bfh_(o);
      y_h[(size_t)n * 384 + d] = hh;
      y_l[(size_t)n * 384 + d] = bfh_(o - bf2f_(hh));
    }
  }
}

extern "C" void kernel_launch(void* const* d_in, const int* in_sizes, int n_in,
                              void* d_out, int out_size, void* d_ws, size_t ws_size,
                              hipStream_t stream) {
  const float* x        = (const float*)d_in[0];
  const float* patch_w  = (const float*)d_in[1];
  const float* patch_b  = (const float*)d_in[2];
  const float* norm_w   = (const float*)d_in[3];
  const float* norm_b   = (const float*)d_in[4];
  const float* in_proj_w  = (const float*)d_in[5];
  const float* conv_w   = (const float*)d_in[6];
  const float* conv_b   = (const float*)d_in[7];
  const float* x_proj_w = (const float*)d_in[8];
  const float* dt_proj_w = (const float*)d_in[9];
  const float* dt_proj_b = (const float*)d_in[10];
  const float* A_log    = (const float*)d_in[11];
  const float* D_param  = (const float*)d_in[12];
  const float* out_proj_w = (const float*)d_in[13];
  const float* normf_w  = (const float*)d_in[14];
  const float* normf_b  = (const float*)d_in[15];
  float* out = (float*)d_out;
  float* ws = (float*)d_ws;

  // fp32 workspace (float offsets)
  float* xz   = ws;                    // 1600*768 = 1228800
  float* xc   = ws + 1228800;          // 602112
  float* dbl  = ws + 1830912;          // 68992
  float* dt   = ws + 1899904;          // 602112
  float* resA = ws + 2502016;          // 307200
  float* resB = ws + 2809216;          // 307200
  float* h    = ws + 3116416;          // 307200
  // bf16 area
  ush* ub = (ush*)(ws + 3423616);
  ush* a_h  = ub;                      // 1600*768
  ush* a_l  = ub + 1228800;
  ush* y_h  = ub + 2457600;            // 1600*384
  ush* y_l  = ub + 3072000;
  ush* pw_h = ub + 3686400;            // 192*768
  ush* pw_l = ub + 3833856;
  ush* ipw_h = ub + 3981312;           // 24*768*192
  ush* ipw_l = ub + 7520256;
  ush* opw_h = ub + 11059200;          // 24*192*384
  ush* opw_l = ub + 12828672;          // end 14598144 ush

  zeros_k<<<294, 256, 0, stream>>>(resA, a_h, a_l, y_h, y_l);
  wsplit3_k<<<(N8_PW + N8_IPW + N8_OPW + 255) / 256, 256, 0, stream>>>(
      patch_w, in_proj_w, out_proj_w, pw_h, pw_l, ipw_h, ipw_l, opw_h, opw_l);
  im2col_k<<<(NROWS * 768 / 8 + 255) / 256, 256, 0, stream>>>(x, a_h, a_l);
  // patch embedding GEMM (M=1600,N=192,K=768): 150 tiles of 32x64
  gemm64_k<<<150, 256, 0, stream>>>(a_h, a_l, pw_h, pw_l, patch_b, h, 192, 768);

  for (int L = 0; L < 24; ++L) {
    const float* rin = (L & 1) ? resB : resA;
    float* rout = (L & 1) ? resA : resB;
    // fused residual+LN + in_proj (600 tiles of 32x64, K=192)
    gemm_inln_k<<<600, 256, 0, stream>>>(rin, rout, h,
        norm_w + L * 192, norm_b + L * 192,
        ipw_h + (size_t)L * 147456, ipw_l + (size_t)L * 147456, xz);
    convdbldt_k<<<NROWS, 384, 0, stream>>>(xz,
        conv_w + (size_t)L * 1536, conv_b + (size_t)L * 384,
        x_proj_w + (size_t)L * 16896,
        dt_proj_w + (size_t)L * 4608, dt_proj_b + (size_t)L * 384,
        xc, dbl, dt);
    scanF_k<<<dim3(8 * 384 / 2), 448, 0, stream>>>(dt, xc, dbl, xz,
        A_log + (size_t)L * 6144, D_param + (size_t)L * 384, y_h, y_l);
    // out_proj (M=1600,N=192,K=384): 300 tiles of 32x32
    gemm32_k<<<300, 256, 0, stream>>>(y_h, y_l,
        opw_h + (size_t)L * 73728, opw_l + (size_t)L * 73728, nullptr, h, 192, 384);
  }

  // final: res(after L23) + h(L23 out) -> LN -> out
  lnfin_k<<<392, 256, 0, stream>>>(resA, h, normf_w, normf_b, out);
}

// Round 11
// 1526.847 us; speedup vs baseline: 5.6920x; 1.1193x over previous
//
#include <hip/hip_runtime.h>

#define NROWS 1568      // BATCH * L = 8 * 196
#define MPAD  1600      // padded rows for GEMM tiles
#define LSEQ  196
#define EPS   1e-5f
#define TCH   14
#define NCH   14

typedef __attribute__((ext_vector_type(8))) short short8_t;   // 8 bf16
typedef __attribute__((ext_vector_type(8))) unsigned short ush8;
typedef __attribute__((ext_vector_type(4))) float f32x4;
typedef unsigned short ush;

__device__ __forceinline__ float silu_(float x) { return x / (1.f + expf(-x)); }

__device__ __forceinline__ ush bfh_(float f) {
  unsigned u = __float_as_uint(f);
  return (ush)((u + 0x7FFFu + ((u >> 16) & 1u)) >> 16);
}
__device__ __forceinline__ float bf2f_(ush h) {
  return __uint_as_float(((unsigned)h) << 16);
}

// async global->LDS, 16B per lane; LDS dest = wave-uniform base + lane*16
__device__ __forceinline__ void glds16(const ush* g, ush* l) {
  __builtin_amdgcn_global_load_lds(
      (const __attribute__((address_space(1))) void*)g,
      (__attribute__((address_space(3))) void*)l, 16, 0, 0);
}

// ---------------- merged weight split: patch_w | in_proj_w | out_proj_w ----------------
#define N8_PW  18432
#define N8_IPW 442368
#define N8_OPW 221184
__global__ __launch_bounds__(256) void wsplit3_k(const float* __restrict__ pw,
                                                 const float* __restrict__ ipw,
                                                 const float* __restrict__ opw,
                                                 ush* __restrict__ pw_h, ush* __restrict__ pw_l,
                                                 ush* __restrict__ ipw_h, ush* __restrict__ ipw_l,
                                                 ush* __restrict__ opw_h, ush* __restrict__ opw_l) {
  int i = blockIdx.x * 256 + threadIdx.x;
  const float* src;
  ush *hi, *lo;
  size_t off;
  if (i < N8_PW) { src = pw; hi = pw_h; lo = pw_l; off = i; }
  else if (i < N8_PW + N8_IPW) { src = ipw; hi = ipw_h; lo = ipw_l; off = i - N8_PW; }
  else if (i < N8_PW + N8_IPW + N8_OPW) { src = opw; hi = opw_h; lo = opw_l; off = i - N8_PW - N8_IPW; }
  else return;
  float v[8];
  *(float4*)&v[0] = *(const float4*)(src + off * 8);
  *(float4*)&v[4] = *(const float4*)(src + off * 8 + 4);
  ush8 h8, l8;
#pragma unroll
  for (int j = 0; j < 8; ++j) {
    ush h = bfh_(v[j]);
    h8[j] = h;
    l8[j] = bfh_(v[j] - bf2f_(h));
  }
  *(ush8*)&hi[off * 8] = h8;
  *(ush8*)&lo[off * 8] = l8;
}

// ---------------- zero res + pad rows of bf16 activation buffers ----------------
__global__ __launch_bounds__(256) void zeros_k(float* __restrict__ res,
                                               ush* __restrict__ a_h, ush* __restrict__ a_l,
                                               ush* __restrict__ hn_h, ush* __restrict__ hn_l,
                                               ush* __restrict__ y_h, ush* __restrict__ y_l) {
  int i = blockIdx.x * 256 + threadIdx.x;
  ush8 z = {};
  if (i < 75264) ((float4*)res)[i] = float4{0.f, 0.f, 0.f, 0.f};
  if (i < 3072) {
    ((ush8*)(a_h + (size_t)NROWS * 768))[i] = z;
    ((ush8*)(a_l + (size_t)NROWS * 768))[i] = z;
  }
  if (i < 768) {
    ((ush8*)(hn_h + (size_t)NROWS * 192))[i] = z;
    ((ush8*)(hn_l + (size_t)NROWS * 192))[i] = z;
  }
  if (i < 1536) {
    ((ush8*)(y_h + (size_t)NROWS * 384))[i] = z;
    ((ush8*)(y_l + (size_t)NROWS * 384))[i] = z;
  }
}

// ---------------- im2col for patch embedding, bf16 hi/lo out ----------------
__global__ __launch_bounds__(256) void im2col_k(const float* __restrict__ x,
                                                ush* __restrict__ Ah,
                                                ush* __restrict__ Al) {
  int i8 = blockIdx.x * 256 + threadIdx.x;
  if (i8 >= NROWS * 768 / 8) return;
  int idx = i8 * 8;
  int m = idx / 768, r = idx - m * 768;
  int b = m / LSEQ, l = m - b * LSEQ;
  int ph = l / 14, pw = l - ph * 14;
  int c = r >> 8, rem = r & 255, ii = rem >> 4, j = rem & 15;
  const float* src = &x[((b * 3 + c) * 224 + ph * 16 + ii) * 224 + pw * 16 + j];
  float v[8];
  *(float4*)&v[0] = *(const float4*)&src[0];
  *(float4*)&v[4] = *(const float4*)&src[4];
  ush8 h8, l8;
#pragma unroll
  for (int k = 0; k < 8; ++k) {
    ush h = bfh_(v[k]);
    h8[k] = h;
    l8[k] = bfh_(v[k] - bf2f_(h));
  }
  *(ush8*)&Ah[idx] = h8;
  *(ush8*)&Al[idx] = l8;
}

// ---------------- 64x64 MFMA GEMM, glds16 + double-buffered LDS, 1 barrier/K-step ------
// LDS[r][c] = global[r][c ^ swz(r)]; read applies same XOR -> content identical to R6.
__global__ __launch_bounds__(256) void gemm64g_k(const ush* __restrict__ Ah_g,
                                                 const ush* __restrict__ Al_g,
                                                 const ush* __restrict__ Wh_g,
                                                 const ush* __restrict__ Wl_g,
                                                 const float* __restrict__ bias,
                                                 float* __restrict__ C, int N, int K) {
  __shared__ ush sAh[2][2048], sAl[2][2048], sWh[2][2048], sWl[2][2048];
  const int tid = threadIdx.x, lane = tid & 63, wave = tid >> 6;
  const int ntiles = N / 64;
  const int row0 = (blockIdx.x / ntiles) * 64, col0 = (blockIdx.x % ntiles) * 64;
  const int sr = wave * 16 + (lane >> 2);                 // LDS row 0..63
  const int j8 = ((lane & 3) ^ ((sr >> 1) & 3)) * 8;      // pre-swizzled src chunk
  const size_t gaA = (size_t)(row0 + sr) * K + j8;
  const size_t gaW = (size_t)(col0 + sr) * K + j8;
  const int lb = wave * 512;                               // wave slice (ush)

  glds16(Ah_g + gaA, &sAh[0][lb]);
  glds16(Al_g + gaA, &sAl[0][lb]);
  glds16(Wh_g + gaW, &sWh[0][lb]);
  glds16(Wl_g + gaW, &sWl[0][lb]);

  const int fr = lane & 15, fg = lane >> 4;
  const int wm = (wave & 1) * 32, wn = (wave >> 1) * 32;
  f32x4 acc[2][2] = {};
  int cur = 0;

  for (int kk = 0; kk < K; kk += 32) {
    __syncthreads();                    // buf[cur] landed; prev-step reads done
    if (kk + 32 < K) {
      int nk = kk + 32;
      glds16(Ah_g + gaA + nk, &sAh[cur ^ 1][lb]);
      glds16(Al_g + gaA + nk, &sAl[cur ^ 1][lb]);
      glds16(Wh_g + gaW + nk, &sWh[cur ^ 1][lb]);
      glds16(Wl_g + gaW + nk, &sWl[cur ^ 1][lb]);
    }
    short8_t ah[2], al[2], wh[2], wl[2];
#pragma unroll
    for (int i = 0; i < 2; ++i) {
      int ra = wm + i * 16 + fr;
      int oa = ra * 32 + ((fg ^ ((ra >> 1) & 3)) << 3);
      ah[i] = *(short8_t*)&sAh[cur][oa];
      al[i] = *(short8_t*)&sAl[cur][oa];
      int rw = wn + i * 16 + fr;
      int ow = rw * 32 + ((fg ^ ((rw >> 1) & 3)) << 3);
      wh[i] = *(short8_t*)&sWh[cur][ow];
      wl[i] = *(short8_t*)&sWl[cur][ow];
    }
#pragma unroll
    for (int i = 0; i < 2; ++i)
#pragma unroll
      for (int j = 0; j < 2; ++j) {
        acc[i][j] = __builtin_amdgcn_mfma_f32_16x16x32_bf16(ah[i], wh[j], acc[i][j], 0, 0, 0);
        acc[i][j] = __builtin_amdgcn_mfma_f32_16x16x32_bf16(ah[i], wl[j], acc[i][j], 0, 0, 0);
        acc[i][j] = __builtin_amdgcn_mfma_f32_16x16x32_bf16(al[i], wh[j], acc[i][j], 0, 0, 0);
      }
    cur ^= 1;
  }

#pragma unroll
  for (int i = 0; i < 2; ++i)
#pragma unroll
    for (int j = 0; j < 2; ++j)
#pragma unroll
      for (int r = 0; r < 4; ++r) {
        int m = row0 + wm + i * 16 + fg * 4 + r;
        int n = col0 + wn + j * 16 + fr;
        float o = acc[i][j][r];
        if (bias) o += bias[n];
        C[(size_t)m * N + n] = o;
      }
}

// ---------------- 32x32 MFMA GEMM, same engine (out_proj) ----------------
__global__ __launch_bounds__(256) void gemm32g_k(const ush* __restrict__ Ah_g,
                                                 const ush* __restrict__ Al_g,
                                                 const ush* __restrict__ Wh_g,
                                                 const ush* __restrict__ Wl_g,
                                                 float* __restrict__ C, int N, int K) {
  __shared__ ush sAh[2][1024], sAl[2][1024], sWh[2][1024], sWl[2][1024];
  const int tid = threadIdx.x, lane = tid & 63, wave = tid >> 6;
  const int ntiles = N / 32;
  const int row0 = (blockIdx.x / ntiles) * 32, col0 = (blockIdx.x % ntiles) * 32;
  const int sr = (wave & 1) * 16 + (lane >> 2);           // 0..31 within panel
  const int j8 = ((lane & 3) ^ ((sr >> 1) & 3)) * 8;
  const bool isA = wave < 2;
  const size_t ga = (size_t)((isA ? row0 : col0) + sr) * K + j8;
  const ush* gh = isA ? Ah_g : Wh_g;
  const ush* gl = isA ? Al_g : Wl_g;
  const int lb = (wave & 1) * 512;

  {
    ush* dh = isA ? &sAh[0][lb] : &sWh[0][lb];
    ush* dl = isA ? &sAl[0][lb] : &sWl[0][lb];
    glds16(gh + ga, dh);
    glds16(gl + ga, dl);
  }

  const int fr = lane & 15, fg = lane >> 4;
  const int wrow = wave & 1, wcol = wave >> 1;
  f32x4 acc = {};
  int cur = 0;

  for (int kk = 0; kk < K; kk += 32) {
    __syncthreads();
    if (kk + 32 < K) {
      int nk = kk + 32;
      ush* dh = isA ? &sAh[cur ^ 1][lb] : &sWh[cur ^ 1][lb];
      ush* dl = isA ? &sAl[cur ^ 1][lb] : &sWl[cur ^ 1][lb];
      glds16(gh + ga + nk, dh);
      glds16(gl + ga + nk, dl);
    }
    int ra = wrow * 16 + fr;
    int oa = ra * 32 + ((fg ^ ((ra >> 1) & 3)) << 3);
    short8_t ah = *(short8_t*)&sAh[cur][oa];
    short8_t al = *(short8_t*)&sAl[cur][oa];
    int rw = wcol * 16 + fr;
    int ow = rw * 32 + ((fg ^ ((rw >> 1) & 3)) << 3);
    short8_t wh = *(short8_t*)&sWh[cur][ow];
    short8_t wl = *(short8_t*)&sWl[cur][ow];
    acc = __builtin_amdgcn_mfma_f32_16x16x32_bf16(ah, wh, acc, 0, 0, 0);
    acc = __builtin_amdgcn_mfma_f32_16x16x32_bf16(ah, wl, acc, 0, 0, 0);
    acc = __builtin_amdgcn_mfma_f32_16x16x32_bf16(al, wh, acc, 0, 0, 0);
    cur ^= 1;
  }

#pragma unroll
  for (int r = 0; r < 4; ++r) {
    int m = row0 + wrow * 16 + fg * 4 + r;
    int n = col0 + wcol * 16 + fr;
    C[(size_t)m * N + n] = acc[r];
  }
}

// ---------------- fused residual-add + LayerNorm -> split-bf16 (R6-verified) ----------
__global__ __launch_bounds__(64) void addlnbf_k(float* __restrict__ res,
                                                const float* __restrict__ h,
                                                const float* __restrict__ w,
                                                const float* __restrict__ b,
                                                ush* __restrict__ out_h,
                                                ush* __restrict__ out_l) {
  int n = blockIdx.x;
  int t = threadIdx.x;
  float v[3];
  float s = 0.f;
#pragma unroll
  for (int i = 0; i < 3; ++i) {
    int d = t + 64 * i;
    float r = res[(size_t)n * 192 + d] + h[(size_t)n * 192 + d];
    res[(size_t)n * 192 + d] = r;
    v[i] = r;
    s += r;
  }
#pragma unroll
  for (int off = 32; off >= 1; off >>= 1) s += __shfl_xor(s, off);
  float mu = s * (1.f / 192.f);
  float q = 0.f;
#pragma unroll
  for (int i = 0; i < 3; ++i) { float dd = v[i] - mu; q += dd * dd; }
#pragma unroll
  for (int off = 32; off >= 1; off >>= 1) q += __shfl_xor(q, off);
  float inv = rsqrtf(q * (1.f / 192.f) + EPS);
#pragma unroll
  for (int i = 0; i < 3; ++i) {
    int d = t + 64 * i;
    float o = (v[i] - mu) * inv * w[d] + b[d];
    ush hh = bfh_(o);
    out_h[(size_t)n * 192 + d] = hh;
    out_l[(size_t)n * 192 + d] = bfh_(o - bf2f_(hh));
  }
}

// ---------------- final residual-add + LayerNorm -> fp32 out ----------------
__global__ __launch_bounds__(256) void lnfin_k(const float* __restrict__ res,
                                               const float* __restrict__ h,
                                               const float* __restrict__ w,
                                               const float* __restrict__ b,
                                               float* __restrict__ out) {
  int n = blockIdx.x * 4 + (threadIdx.x >> 6);
  int lane = threadIdx.x & 63;
  if (n >= NROWS) return;
  float v[3];
  float s = 0.f;
#pragma unroll
  for (int i = 0; i < 3; ++i) {
    int d = lane + 64 * i;
    float r = res[(size_t)n * 192 + d] + h[(size_t)n * 192 + d];
    v[i] = r;
    s += r;
  }
#pragma unroll
  for (int off = 32; off >= 1; off >>= 1) s += __shfl_xor(s, off);
  float mu = s * (1.f / 192.f);
  float q = 0.f;
#pragma unroll
  for (int i = 0; i < 3; ++i) { float dd = v[i] - mu; q += dd * dd; }
#pragma unroll
  for (int off = 32; off >= 1; off >>= 1) q += __shfl_xor(q, off);
  float inv = rsqrtf(q * (1.f / 192.f) + EPS);
#pragma unroll
  for (int i = 0; i < 3; ++i) {
    int d = lane + 64 * i;
    out[(size_t)n * 192 + d] = (v[i] - mu) * inv * w[d] + b[d];
  }
}

// ---------------- conv4+SiLU + x_proj + dt_proj, 4 rows/block (weights amortized) ------
__global__ __launch_bounds__(384) void conv4_k(const float* __restrict__ xz,
                                               const float* __restrict__ cw,
                                               const float* __restrict__ cb,
                                               const float* __restrict__ xpw,
                                               const float* __restrict__ dtw,
                                               const float* __restrict__ dtb,
                                               float* __restrict__ xc,
                                               float* __restrict__ dbl,
                                               float* __restrict__ dt) {
  __shared__ __align__(16) float xcl[4][384];
  __shared__ __align__(16) float dbll[4][48];
  const int t = threadIdx.x;
  const int n0 = blockIdx.x * 4;
  const int l0 = n0 % LSEQ;          // 4 | 196 so the 4 rows share b

  // conv phase: weights in regs, 4 rows sequential
  float cwv[4];
  *(float4*)cwv = *(const float4*)(cw + t * 4);
  float cbv = cb[t];
#pragma unroll
  for (int r = 0; r < 4; ++r) {
    int l = l0 + r, n = n0 + r;
    float acc = cbv;
#pragma unroll
    for (int k = 0; k < 4; ++k) {
      int ll = l - 3 + k;
      if (ll >= 0) acc += xz[(size_t)(n - 3 + k) * 768 + t] * cwv[k];
    }
    float v = silu_(acc);
    xcl[r][t] = v;
    xc[(size_t)n * 384 + t] = v;
  }
  __syncthreads();

  // x_proj phase: weights loaded once, applied to 4 rows
  if (t < 352) {
    const int e = t >> 3, part = t & 7;
    const float4* w4 = (const float4*)(xpw + e * 384 + part * 48);
    const float4* x0 = (const float4*)(&xcl[0][part * 48]);
    const float4* x1 = (const float4*)(&xcl[1][part * 48]);
    const float4* x2 = (const float4*)(&xcl[2][part * 48]);
    const float4* x3 = (const float4*)(&xcl[3][part * 48]);
    float s0 = 0.f, s1 = 0.f, s2 = 0.f, s3 = 0.f;
#pragma unroll
    for (int k = 0; k < 12; ++k) {
      float4 w = w4[k], a;
      a = x0[k]; s0 += a.x * w.x + a.y * w.y + a.z * w.z + a.w * w.w;
      a = x1[k]; s1 += a.x * w.x + a.y * w.y + a.z * w.z + a.w * w.w;
      a = x2[k]; s2 += a.x * w.x + a.y * w.y + a.z * w.z + a.w * w.w;
      a = x3[k]; s3 += a.x * w.x + a.y * w.y + a.z * w.z + a.w * w.w;
    }
#pragma unroll
    for (int off = 1; off <= 4; off <<= 1) {
      s0 += __shfl_xor(s0, off);
      s1 += __shfl_xor(s1, off);
      s2 += __shfl_xor(s2, off);
      s3 += __shfl_xor(s3, off);
    }
    if (part == 0) {
      dbll[0][e] = s0; dbl[(size_t)(n0 + 0) * 44 + e] = s0;
      dbll[1][e] = s1; dbl[(size_t)(n0 + 1) * 44 + e] = s1;
      dbll[2][e] = s2; dbl[(size_t)(n0 + 2) * 44 + e] = s2;
      dbll[3][e] = s3; dbl[(size_t)(n0 + 3) * 44 + e] = s3;
    }
  }
  __syncthreads();

  // dt phase: weights loaded once, 4 rows
  const float4* dw4 = (const float4*)(dtw + t * 12);
  float4 dw0 = dw4[0], dw1 = dw4[1], dw2 = dw4[2];
  float dtbv = dtb[t];
#pragma unroll
  for (int r = 0; r < 4; ++r) {
    const float4* bb = (const float4*)(&dbll[r][0]);
    float4 b0 = bb[0], b1 = bb[1], b2 = bb[2];
    float a = dtbv
            + dw0.x * b0.x + dw0.y * b0.y + dw0.z * b0.z + dw0.w * b0.w
            + dw1.x * b1.x + dw1.y * b1.y + dw1.z * b1.z + dw1.w * b1.w
            + dw2.x * b2.x + dw2.y * b2.y + dw2.z * b2.z + dw2.w * b2.w;
    float sp = fmaxf(a, 0.f) + log1pf(expf(-fabsf(a)));
    dt[(size_t)(n0 + r) * 384 + t] = sp;
  }
}

// ---------------- fused single-kernel chunked scan (R6-verified) ----------------
__global__ __launch_bounds__(448) void scanF_k(const float* __restrict__ dt,
                                               const float* __restrict__ xc,
                                               const float* __restrict__ dbl,
                                               const float* __restrict__ xz,
                                               const float* __restrict__ a_log,
                                               const float* __restrict__ dpar,
                                               ush* __restrict__ y_h,
                                               ush* __restrict__ y_l) {
  __shared__ float Pl[2][NCH][17];
  __shared__ float Sl[2][NCH][17];
  int t = threadIdx.x;
  int p = t / 224;
  int r = t - p * 224;
  int c = r >> 4, s = r & 15;
  int bd = blockIdx.x * 2 + p;
  int b = bd / 384, d = bd - b * 384;
  float A = -expf(a_log[d * 16 + s]);
  float Dp = dpar[d];

  float a_c[TCH], u_c[TCH], C_c[TCH], dx_c[TCH], gz_c[TCH];
  float h = 0.f, pr = 1.f;
  int base = b * LSEQ + c * TCH;
#pragma unroll
  for (int i = 0; i < TCH; ++i) {
    int n = base + i;
    float dtv = dt[(size_t)n * 384 + d];
    float xcv = xc[(size_t)n * 384 + d];
    float Bv  = dbl[(size_t)n * 44 + 12 + s];
    float Cv  = dbl[(size_t)n * 44 + 28 + s];
    float zv  = xz[(size_t)n * 768 + 384 + d];
    float a = expf(dtv * A);
    float u = dtv * xcv * Bv;
    h = a * h + u;
    pr *= a;
    a_c[i] = a; u_c[i] = u; C_c[i] = Cv;
    dx_c[i] = Dp * xcv; gz_c[i] = silu_(zv);
  }
  Pl[p][c][s] = pr;
  Sl[p][c][s] = h;
  __syncthreads();

#pragma unroll
  for (int off = 1; off < NCH; off <<= 1) {
    float Pp = 1.f, Sp = 0.f;
    if (c >= off) { Pp = Pl[p][c - off][s]; Sp = Sl[p][c - off][s]; }
    __syncthreads();
    if (c >= off) {
      float Pc = Pl[p][c][s], Sc = Sl[p][c][s];
      Pl[p][c][s] = Pc * Pp;
      Sl[p][c][s] = Pc * Sp + Sc;
    }
    __syncthreads();
  }

  h = (c > 0) ? Sl[p][c - 1][s] : 0.f;
#pragma unroll
  for (int i = 0; i < TCH; ++i) {
    h = a_c[i] * h + u_c[i];
    float ps = h * C_c[i];
    ps += __shfl_xor(ps, 1);
    ps += __shfl_xor(ps, 2);
    ps += __shfl_xor(ps, 4);
    ps += __shfl_xor(ps, 8);
    if (s == 0) {
      int n = base + i;
      float o = (ps + dx_c[i]) * gz_c[i];
      ush hh = bfh_(o);
      y_h[(size_t)n * 384 + d] = hh;
      y_l[(size_t)n * 384 + d] = bfh_(o - bf2f_(hh));
    }
  }
}

extern "C" void kernel_launch(void* const* d_in, const int* in_sizes, int n_in,
                              void* d_out, int out_size, void* d_ws, size_t ws_size,
                              hipStream_t stream) {
  const float* x        = (const float*)d_in[0];
  const float* patch_w  = (const float*)d_in[1];
  const float* patch_b  = (const float*)d_in[2];
  const float* norm_w   = (const float*)d_in[3];
  const float* norm_b   = (const float*)d_in[4];
  const float* in_proj_w  = (const float*)d_in[5];
  const float* conv_w   = (const float*)d_in[6];
  const float* conv_b   = (const float*)d_in[7];
  const float* x_proj_w = (const float*)d_in[8];
  const float* dt_proj_w = (const float*)d_in[9];
  const float* dt_proj_b = (const float*)d_in[10];
  const float* A_log    = (const float*)d_in[11];
  const float* D_param  = (const float*)d_in[12];
  const float* out_proj_w = (const float*)d_in[13];
  const float* normf_w  = (const float*)d_in[14];
  const float* normf_b  = (const float*)d_in[15];
  float* out = (float*)d_out;
  float* ws = (float*)d_ws;

  // fp32 workspace (float offsets)
  float* res = ws;                     // 301056
  float* xz  = ws + 301056;            // 1600*768 = 1228800
  float* xc  = ws + 1529856;           // 602112
  float* dbl = ws + 2131968;           // 68992
  float* dt  = ws + 2200960;           // 602112
  float* h   = ws + 2803072;           // 1600*192 = 307200
  // bf16 area
  ush* ub = (ush*)(ws + 3110272);
  ush* a_h  = ub;                      // 1600*768
  ush* a_l  = ub + 1228800;
  ush* hn_h = ub + 2457600;            // 1600*192
  ush* hn_l = ub + 2764800;
  ush* y_h  = ub + 3072000;            // 1600*384
  ush* y_l  = ub + 3686400;
  ush* pw_h = ub + 4300800;            // 192*768
  ush* pw_l = ub + 4448256;
  ush* ipw_h = ub + 4595712;           // 24*768*192
  ush* ipw_l = ub + 8134656;
  ush* opw_h = ub + 11673600;          // 24*192*384
  ush* opw_l = ub + 13443072;          // end 15212544 ush

  zeros_k<<<294, 256, 0, stream>>>(res, a_h, a_l, hn_h, hn_l, y_h, y_l);
  wsplit3_k<<<(N8_PW + N8_IPW + N8_OPW + 255) / 256, 256, 0, stream>>>(
      patch_w, in_proj_w, out_proj_w, pw_h, pw_l, ipw_h, ipw_l, opw_h, opw_l);
  im2col_k<<<(NROWS * 768 / 8 + 255) / 256, 256, 0, stream>>>(x, a_h, a_l);
  // patch embedding (M=1600, N=192, K=768): 25x3 = 75 tiles of 64x64
  gemm64g_k<<<75, 256, 0, stream>>>(a_h, a_l, pw_h, pw_l, patch_b, h, 192, 768);

  for (int L = 0; L < 24; ++L) {
    addlnbf_k<<<NROWS, 64, 0, stream>>>(res, h, norm_w + L * 192, norm_b + L * 192, hn_h, hn_l);
    // in_proj (M=1600, N=768, K=192): 25x12 = 300 tiles of 64x64
    gemm64g_k<<<300, 256, 0, stream>>>(hn_h, hn_l,
        ipw_h + (size_t)L * 147456, ipw_l + (size_t)L * 147456, nullptr, xz, 768, 192);
    conv4_k<<<NROWS / 4, 384, 0, stream>>>(xz,
        conv_w + (size_t)L * 1536, conv_b + (size_t)L * 384,
        x_proj_w + (size_t)L * 16896,
        dt_proj_w + (size_t)L * 4608, dt_proj_b + (size_t)L * 384,
        xc, dbl, dt);
    scanF_k<<<dim3(8 * 384 / 2), 448, 0, stream>>>(dt, xc, dbl, xz,
        A_log + (size_t)L * 6144, D_param + (size_t)L * 384, y_h, y_l);
    // out_proj (M=1600, N=192, K=384): 50x6 = 300 tiles of 32x32
    gemm32g_k<<<300, 256, 0, stream>>>(y_h, y_l,
        opw_h + (size_t)L * 73728, opw_l + (size_t)L * 73728, h, 192, 384);
  }

  lnfin_k<<<392, 256, 0, stream>>>(res, h, normf_w, normf_b, out);
}